// Round 15
// baseline (143.806 us; speedup 1.0000x reference)
//
#include <hip/hip_runtime.h>
#include <math.h>

#define SPAT 1600
#define BSZ 8
#define DM 256
#define NH 8
#define DH 32
#define NC16 100  // SPAT/16 c-tiles in K=16 V^T fragment layout

typedef __attribute__((ext_vector_type(8))) short bf16x8;
typedef __attribute__((ext_vector_type(4))) short bf16x4;
typedef __attribute__((ext_vector_type(4))) float f32x4;
typedef __attribute__((ext_vector_type(4))) unsigned short u16x4;

static __device__ __forceinline__ unsigned short f2bf(float x) {
  unsigned u = __float_as_uint(x);
  unsigned r = (u + 0x7fff + ((u >> 16) & 1)) >> 16;
  return (unsigned short)r;
}
static __device__ __forceinline__ float bf2f(unsigned short h) {
  return __uint_as_float(((unsigned)h) << 16);
}

// ---------------- K1: logits[b][s] = k[s][b][:] . Wp + bp ----------------
__global__ __launch_bounds__(256) void logits_kernel(
    const float* __restrict__ k, const float* __restrict__ Wp,
    const float* __restrict__ bp, float* __restrict__ logits)
{
  int wave = threadIdx.x >> 6, lane = threadIdx.x & 63;
  int idx = blockIdx.x * 4 + wave;           // 0..12799
  if (idx >= BSZ * SPAT) return;
  int b = idx / SPAT, s = idx - b * SPAT;
  const float4 kv = *(const float4*)(k + (s * BSZ + b) * DM + lane * 4);
  const float4 wv = *(const float4*)(Wp + lane * 4);
  float sum = kv.x * wv.x + kv.y * wv.y + kv.z * wv.z + kv.w * wv.w;
  #pragma unroll
  for (int off = 32; off; off >>= 1) sum += __shfl_xor(sum, off);
  if (lane == 0) logits[idx] = sum + bp[0];
}

// -------- K2: per-batch softmax -> entropy -> gaussian conv (512 thr) --------
__global__ __launch_bounds__(512) void entropy_kernel(
    const float* __restrict__ logits, const float* __restrict__ gk,
    float* __restrict__ smooth)
{
  int b = blockIdx.x;
  int t = threadIdx.x;
  const float* L = logits + b * SPAT;
  __shared__ float entpad[SPAT + 28];
  __shared__ float red[512];

  for (int i = t; i < SPAT + 28; i += 512) entpad[i] = 0.f;

  float m = -INFINITY;
  for (int i = t; i < SPAT; i += 512) m = fmaxf(m, L[i]);
  red[t] = m; __syncthreads();
  for (int o = 256; o; o >>= 1) { if (t < o) red[t] = fmaxf(red[t], red[t + o]); __syncthreads(); }
  m = red[0]; __syncthreads();

  float lsum = 0.f;
  for (int i = t; i < SPAT; i += 512) {
    float e = expf(L[i] - m);
    entpad[14 + i] = e;
    lsum += e;
  }
  red[t] = lsum; __syncthreads();
  for (int o = 256; o; o >>= 1) { if (t < o) red[t] += red[t + o]; __syncthreads(); }
  float S = red[0]; __syncthreads();

  for (int i = t; i < SPAT; i += 512) {
    float p = entpad[14 + i] / S + 1e-8f;
    entpad[14 + i] = -p * logf(p) / 0.6931471805599453f;
  }
  __syncthreads();

  for (int i = t; i < SPAT; i += 512) {
    float acc = 0.f;
    #pragma unroll
    for (int u = 0; u < 29; ++u) acc += entpad[i + u] * gk[28 - u];
    smooth[b * SPAT + i] = acc;
  }
}

// -------- K3: cluster size; wave w = batch w, shfl-reduce, no atomics --------
__global__ __launch_bounds__(512) void clsize_kernel(
    const float* __restrict__ smooth, const float* __restrict__ sobel,
    int* __restrict__ meta)
{
  __shared__ int cnts[8];
  int t = threadIdx.x;
  int w = t >> 6, lane = t & 63;
  float sb0 = sobel[0], sb1 = sobel[1], sb2 = sobel[2];
  const float* sm = smooth + w * SPAT;
  int local = 0;
  for (int i = 1 + lane; i < SPAT; i += 64) {
    float smL = (i >= 2) ? sm[i - 2] : 0.f;
    float a = sm[i - 1];
    float c = sm[i];
    float smR = (i + 1 < SPAT) ? sm[i + 1] : 0.f;
    float stepPrev = smL * sb2 + a * sb1 + c * sb0;
    float stepCur  = a * sb2 + c * sb1 + smR * sb0;
    local += ((stepPrev > 0.f) != (stepCur > 0.f));
  }
  #pragma unroll
  for (int off = 32; off; off >>= 1) local += __shfl_xor(local, off);
  if (lane == 0) cnts[w] = local;
  __syncthreads();
  if (t == 0) {
    float msum = 0.f;
    for (int b = 0; b < BSZ; ++b) msum += 1600.f / (float)(cnts[b] + 1);
    float mean = msum / 8.f;
    int C = (int)rintf(mean);
    if (C < 1) C = 1;
    int rem = SPAT % C;
    meta[0] = C; meta[1] = rem / 2; meta[2] = rem; meta[3] = (SPAT - rem) / C;
  }
}

// -------- K4: cluster pooling; serial per-thread softmax (no barriers),
// emits kc/vc as bf16 hi/lo A-fragments --------
__global__ __launch_bounds__(256) void cluster_kernel(
    const float* __restrict__ k, const float* __restrict__ v,
    const float* __restrict__ smooth, const int* __restrict__ meta,
    unsigned short* __restrict__ kcfh, unsigned short* __restrict__ kcfl,
    unsigned short* __restrict__ vcfh, unsigned short* __restrict__ vcfl)
{
  int c = blockIdx.x, b = blockIdx.y;
  int C = meta[0], lo = meta[1], n_cl = meta[3];
  if (c >= n_cl) return;
  const float* sm = smooth + b * SPAT + lo + c * C;

  // wave-uniform serial softmax over C (typically ~10) — zero barriers
  float m = sm[0];
  for (int j = 1; j < C; ++j) m = fmaxf(m, sm[j]);
  float S = 0.f;
  for (int j = 0; j < C; ++j) S += __expf(sm[j] - m);
  float invS = 1.f / S;

  int d = threadIdx.x;
  int s0 = lo + c * C;
  const float* kp = k + (s0 * BSZ + b) * DM + d;
  const float* vp = v + (s0 * BSZ + b) * DM + d;
  float ak = 0.f, av = 0.f;
  for (int j = 0; j < C; ++j) {
    float wj = __expf(sm[j] - m) * invS;
    ak += wj * kp[0];
    av += wj * vp[0];
    kp += BSZ * DM; vp += BSZ * DM;
  }
  int rowg = b * SPAT + c;
  size_t dst = (((size_t)(rowg >> 4) * 8 + (d >> 5)) * 64
                + ((d >> 3) & 3) * 16 + (rowg & 15)) * 8 + (d & 7);
  unsigned short hb = f2bf(ak);
  kcfh[dst] = hb; kcfl[dst] = (unsigned short)f2bf(ak - bf2f(hb));
  hb = f2bf(av);
  vcfh[dst] = hb; vcfl[dst] = (unsigned short)f2bf(av - bf2f(hb));
}

// -------- P0: fused prepw (W -> B-frags) + splitq (q -> A-frags) --------
__global__ __launch_bounds__(256) void prep_kernel(
    const float* __restrict__ q,
    const float* __restrict__ Wq, const float* __restrict__ Wk,
    const float* __restrict__ Wv, const float* __restrict__ Wo,
    unsigned short* __restrict__ qfh, unsigned short* __restrict__ qfl,
    unsigned short* __restrict__ WTh, unsigned short* __restrict__ WTl)
{
  int bx = blockIdx.x;
  if (bx < 1600) {
    // splitq: q (s,b,d) fp32 -> A-fragment-linear bf16 hi/lo
    int tg = bx * 256 + threadIdx.x;
    int row = tg >> 5;                       // b*1600+s
    int d0 = (tg & 31) * 8;
    int b = row / SPAT, s = row - b * SPAT;
    const float* src = q + (size_t)(s * BSZ + b) * DM + d0;
    float4 a = *(const float4*)src;
    float4 c = *(const float4*)(src + 4);
    float xs[8] = {a.x, a.y, a.z, a.w, c.x, c.y, c.z, c.w};
    bf16x8 hv, lv;
    #pragma unroll
    for (int j = 0; j < 8; ++j) {
      unsigned short hb = f2bf(xs[j]);
      hv[j] = (short)hb;
      lv[j] = (short)f2bf(xs[j] - bf2f(hb));
    }
    size_t dst = (((size_t)(row >> 4) * 8 + (d0 >> 5)) * 64
                  + ((d0 >> 3) & 3) * 16 + (row & 15)) * 8;
    *(bf16x8*)(qfh + dst) = hv;
    *(bf16x8*)(qfl + dst) = lv;
  } else {
    // prepw: W[k][n] -> B-frag elem (((mat*16+ntile)*8+ktile)*64+g*16+sig)*8+e
    int mb = bx - 1600;
    int mat = mb >> 3, ktile = mb & 7;
    const float* W = (mat == 0) ? Wq : (mat == 1) ? Wk : (mat == 2) ? Wv : Wo;
    int n = threadIdx.x;
    int ntile = n >> 4, sig = n & 15;
    size_t base = (((size_t)(mat * 16 + ntile) * 8 + ktile) * 64 + sig) * 8;
    #pragma unroll 4
    for (int i = 0; i < 32; ++i) {
      int kk = ktile * 32 + i;
      float x = W[kk * DM + n];
      unsigned short hb = f2bf(x);
      size_t dst = base + (size_t)(i >> 3) * 128 + (i & 7);
      WTh[dst] = hb;
      WTl[dst] = (unsigned short)f2bf(x - bf2f(hb));
    }
  }
}

// -------- shared GEMM body: fragment-linear operands, bf16x3 --------
// epi: 0 = bf16 hi/lo [bh][s|c][32]
//      1 = K=16 V^T A-frags [bh][c16][dhalf][lane][4]
//      2 = fp32 out[(s*8+b)*256+n]
static __device__ __forceinline__ void gemm_body(
    const unsigned short* __restrict__ Afh, const unsigned short* __restrict__ Afl,
    const unsigned short* __restrict__ Bfh, const unsigned short* __restrict__ Bfl,
    const float* __restrict__ bias,
    unsigned short* __restrict__ Oh, unsigned short* __restrict__ Ol,
    float* __restrict__ Of, int epi, int skipcl, const int* __restrict__ meta)
{
  int row0blk = blockIdx.x * 64;
  if (skipcl && (row0blk % SPAT) >= meta[3]) return;
  int wv = threadIdx.x >> 6, l = threadIdx.x & 63;
  int g = l >> 4, sig = l & 15;
  int row0 = row0blk + wv * 16;
  int rtile = row0 >> 4;
  int col0 = blockIdx.y * 64;
  int ntile0 = col0 >> 4;

  f32x4 acc[4] = {{0.f,0.f,0.f,0.f},{0.f,0.f,0.f,0.f},{0.f,0.f,0.f,0.f},{0.f,0.f,0.f,0.f}};

  #pragma unroll 1
  for (int kt = 0; kt < 8; ++kt) {
    size_t ao = (((size_t)rtile * 8 + kt) * 64 + l) * 8;
    bf16x8 ah = *(const bf16x8*)(Afh + ao);
    bf16x8 al = *(const bf16x8*)(Afl + ao);
    #pragma unroll
    for (int nt = 0; nt < 4; ++nt) {
      size_t bo = (((size_t)(ntile0 + nt) * 8 + kt) * 64 + l) * 8;
      bf16x8 bh = *(const bf16x8*)(Bfh + bo);
      bf16x8 bl = *(const bf16x8*)(Bfl + bo);
      acc[nt] = __builtin_amdgcn_mfma_f32_16x16x32_bf16(ah, bh, acc[nt], 0, 0, 0);
      acc[nt] = __builtin_amdgcn_mfma_f32_16x16x32_bf16(al, bh, acc[nt], 0, 0, 0);
      acc[nt] = __builtin_amdgcn_mfma_f32_16x16x32_bf16(ah, bl, acc[nt], 0, 0, 0);
    }
  }

  int bb = row0 / SPAT;
  int sbase = row0 - bb * SPAT + 4 * g;
  #pragma unroll
  for (int nt = 0; nt < 4; ++nt) {
    int n = col0 + nt * 16 + sig;
    float bi = bias[n];
    if (epi == 0) {
      int h = n >> 5, dl = n & 31;
      size_t base = (size_t)(bb * NH + h) * SPAT * DH + dl;
      #pragma unroll
      for (int r = 0; r < 4; ++r) {
        float x = acc[nt][r] + bi;
        unsigned short hb = f2bf(x);
        size_t dst = base + (size_t)(sbase + r) * DH;
        Oh[dst] = hb;
        Ol[dst] = (unsigned short)f2bf(x - bf2f(hb));
      }
    } else if (epi == 1) {
      // element: V[c = sbase+r][d = n] -> A-frag of 16x16x16 PV MFMA:
      // [bh][c>>4][(n&31)>>4][lane = ((c>>2)&3)*16 + (n&15)][c&3]
      int h = n >> 5;
      int bh = bb * NH + h;
      int dhalf = (n & 31) >> 4;
      int mrow = n & 15;
      #pragma unroll
      for (int r = 0; r < 4; ++r) {
        int c = sbase + r;
        float x = acc[nt][r] + bi;
        unsigned short hb = f2bf(x);
        size_t dst = ((((size_t)bh * NC16 + (c >> 4)) * 2 + dhalf) * 64
                      + ((c >> 2) & 3) * 16 + mrow) * 4 + (c & 3);
        Oh[dst] = hb;
        Ol[dst] = (unsigned short)f2bf(x - bf2f(hb));
      }
    } else {
      #pragma unroll
      for (int r = 0; r < 4; ++r) {
        float x = acc[nt][r] + bi;
        Of[(size_t)((sbase + r) * BSZ + bb) * DM + n] = x;
      }
    }
  }
}

// -------- K5a: fused Q/K/V projection GEMMs (blockIdx.z selects) --------
__global__ __launch_bounds__(256) void mfma_gemm_qkv_kernel(
    const unsigned short* __restrict__ qfh, const unsigned short* __restrict__ qfl,
    const unsigned short* __restrict__ kcfh, const unsigned short* __restrict__ kcfl,
    const unsigned short* __restrict__ vcfh, const unsigned short* __restrict__ vcfl,
    const unsigned short* __restrict__ WTfh, const unsigned short* __restrict__ WTfl,
    const float* __restrict__ bq, const float* __restrict__ bk, const float* __restrict__ bv,
    unsigned short* __restrict__ Qh, unsigned short* __restrict__ Ql,
    unsigned short* __restrict__ Kh, unsigned short* __restrict__ Kl,
    unsigned short* __restrict__ Vth, unsigned short* __restrict__ Vtl,
    const int* __restrict__ meta)
{
  int z = blockIdx.z;
  if (z == 0) {
    gemm_body(qfh, qfl, WTfh, WTfl, bq, Qh, Ql, nullptr, 0, 0, meta);
  } else if (z == 1) {
    gemm_body(kcfh, kcfl, WTfh + DM * DM, WTfl + DM * DM, bk, Kh, Kl, nullptr, 0, 1, meta);
  } else {
    gemm_body(vcfh, vcfl, WTfh + 2 * DM * DM, WTfl + 2 * DM * DM, bv, Vth, Vtl, nullptr, 1, 1, meta);
  }
}

// -------- K5b: output GEMM (epi=2, fp32 out + transpose) --------
__global__ __launch_bounds__(256) void mfma_gemm_o_kernel(
    const unsigned short* __restrict__ Afh, const unsigned short* __restrict__ Afl,
    const unsigned short* __restrict__ Bfh, const unsigned short* __restrict__ Bfl,
    const float* __restrict__ bias, float* __restrict__ Of,
    const int* __restrict__ meta)
{
  gemm_body(Afh, Afl, Bfh, Bfl, bias, nullptr, nullptr, Of, 2, 0, meta);
}

// -------- K6: MFMA attention, 128-cluster chunks for memory-level
// parallelism. Round-14 PMC: VGPR=52, eff. BW 965 GB/s, all pipes <30% —
// latency-bound at MLP~2.5 (compiler register-minimized the loads).
// This version holds a full chunk's V frags (32 x 8B) + pipelined K loads
// in registers (~140 VGPR) so ~4-8x more loads are in flight. PV uses 4
// split accumulators (half chain depth); lsum is a 4-way partial tree.
__global__ __launch_bounds__(256) void attn_mfma_kernel(
    const unsigned short* __restrict__ Qh, const unsigned short* __restrict__ Ql,
    const unsigned short* __restrict__ Kh, const unsigned short* __restrict__ Kl,
    const unsigned short* __restrict__ Vth, const unsigned short* __restrict__ Vtl,
    const int* __restrict__ meta,
    unsigned short* __restrict__ ctxfh, unsigned short* __restrict__ ctxfl)
{
  int b = blockIdx.y, h = blockIdx.z, bh = b * NH + h;
  int t = threadIdx.x;
  int w = t >> 6, l = t & 63;
  int g = l >> 4, sig = l & 15;
  int n_cl = meta[3];
  int s = blockIdx.x * 64 + w * 16 + sig;   // 25*64 = 1600

  size_t qoff = ((size_t)bh * SPAT + s) * DH + g * 8;
  bf16x8 qh = *(const bf16x8*)(Qh + qoff);
  bf16x8 ql = *(const bf16x8*)(Ql + qoff);

  const unsigned short* Kbh = Kh + (size_t)bh * SPAT * DH;
  const unsigned short* Kbl = Kl + (size_t)bh * SPAT * DH;
  const unsigned short* Vbh = Vth + (size_t)bh * NC16 * 2 * 64 * 4;
  const unsigned short* Vbl = Vtl + (size_t)bh * NC16 * 2 * 64 * 4;

  f32x4 o0a = {0.f,0.f,0.f,0.f}, o0b = {0.f,0.f,0.f,0.f};
  f32x4 o1a = {0.f,0.f,0.f,0.f}, o1b = {0.f,0.f,0.f,0.f};
  float m = -1e30f, lsum = 0.f;

  for (int c0 = 0; c0 < n_cl; c0 += 128) {
    // ---- QK^T: 8 tiles; K loads pipeline tile-to-tile ----
    f32x4 sc[8];
    __builtin_amdgcn_s_setprio(1);
    #pragma unroll
    for (int ct = 0; ct < 8; ++ct) {
      int cr = c0 + ct * 16 + sig;
      if (cr > SPAT - 1) cr = SPAT - 1;     // clamped rows get -inf masked
      size_t ko = (size_t)cr * DH + g * 8;
      bf16x8 kh = *(const bf16x8*)(Kbh + ko);
      bf16x8 kl = *(const bf16x8*)(Kbl + ko);
      f32x4 a = {0.f, 0.f, 0.f, 0.f};
      a = __builtin_amdgcn_mfma_f32_16x16x32_bf16(kh, qh, a, 0, 0, 0);
      a = __builtin_amdgcn_mfma_f32_16x16x32_bf16(kh, ql, a, 0, 0, 0);
      a = __builtin_amdgcn_mfma_f32_16x16x32_bf16(kl, qh, a, 0, 0, 0);
      sc[ct] = a;
    }
    __builtin_amdgcn_s_setprio(0);

    // ---- V frags for the whole chunk: 32 loads in named regs (MLP) ----
    bf16x4 vfh[8][2], vfl[8][2];
    #pragma unroll
    for (int ct = 0; ct < 8; ++ct) {
      int c16 = (c0 >> 4) + ct;
      if (c16 > NC16 - 1) c16 = NC16 - 1;   // clamped tiles get p=0
      #pragma unroll
      for (int dh2 = 0; dh2 < 2; ++dh2) {
        size_t vo = (((size_t)c16 * 2 + dh2) * 64 + l) * 4;
        vfh[ct][dh2] = *(const bf16x4*)(Vbh + vo);
        vfl[ct][dh2] = *(const bf16x4*)(Vbl + vo);
      }
    }

    if (c0 + 128 > n_cl) {                  // tail chunk only: mask
      #pragma unroll
      for (int ct = 0; ct < 8; ++ct) {
        #pragma unroll
        for (int r = 0; r < 4; ++r) {
          int c = c0 + ct * 16 + g * 4 + r;
          if (c >= n_cl) sc[ct][r] = -INFINITY;
        }
      }
    }
    // ---- chunk max (tree) ----
    float mc01 = sc[0][0], mc23 = sc[2][0], mc45 = sc[4][0], mc67 = sc[6][0];
    #pragma unroll
    for (int r = 0; r < 4; ++r) {
      mc01 = fmaxf(mc01, fmaxf(sc[0][r], sc[1][r]));
      mc23 = fmaxf(mc23, fmaxf(sc[2][r], sc[3][r]));
      mc45 = fmaxf(mc45, fmaxf(sc[4][r], sc[5][r]));
      mc67 = fmaxf(mc67, fmaxf(sc[6][r], sc[7][r]));
    }
    float mc = fmaxf(fmaxf(mc01, mc23), fmaxf(mc45, mc67));
    mc = fmaxf(mc, __shfl_xor(mc, 16));
    mc = fmaxf(mc, __shfl_xor(mc, 32));
    float nm = fmaxf(m, mc);
    float corr = __expf(m - nm);
    m = nm;
    lsum *= corr;
    o0a *= corr; o0b *= corr; o1a *= corr; o1b *= corr;
    // ---- p = exp(sc - m); 4-way partial denominators ----
    float ls0 = 0.f, ls1 = 0.f, ls2 = 0.f, ls3 = 0.f;
    #pragma unroll
    for (int ct = 0; ct < 8; ++ct) {
      #pragma unroll
      for (int r = 0; r < 4; ++r) {
        float p = __expf(sc[ct][r] - m);
        sc[ct][r] = p;
        if (ct < 2) ls0 += p; else if (ct < 4) ls1 += p;
        else if (ct < 6) ls2 += p; else ls3 += p;
      }
    }
    lsum += (ls0 + ls1) + (ls2 + ls3);

    // ---- PV: P fed directly from QK output regs (K=16); split chains ----
    __builtin_amdgcn_s_setprio(1);
    #pragma unroll
    for (int ct = 0; ct < 8; ++ct) {
      if (c0 + ct * 16 >= n_cl) continue;   // wave-uniform skip
      bf16x4 pb;
      #pragma unroll
      for (int j = 0; j < 4; ++j) pb[j] = (short)f2bf(sc[ct][j]);
      if (ct < 4) {
        o0a = __builtin_amdgcn_mfma_f32_16x16x16bf16_1k(vfh[ct][0], pb, o0a, 0, 0, 0);
        o0a = __builtin_amdgcn_mfma_f32_16x16x16bf16_1k(vfl[ct][0], pb, o0a, 0, 0, 0);
        o1a = __builtin_amdgcn_mfma_f32_16x16x16bf16_1k(vfh[ct][1], pb, o1a, 0, 0, 0);
        o1a = __builtin_amdgcn_mfma_f32_16x16x16bf16_1k(vfl[ct][1], pb, o1a, 0, 0, 0);
      } else {
        o0b = __builtin_amdgcn_mfma_f32_16x16x16bf16_1k(vfh[ct][0], pb, o0b, 0, 0, 0);
        o0b = __builtin_amdgcn_mfma_f32_16x16x16bf16_1k(vfl[ct][0], pb, o0b, 0, 0, 0);
        o1b = __builtin_amdgcn_mfma_f32_16x16x16bf16_1k(vfh[ct][1], pb, o1b, 0, 0, 0);
        o1b = __builtin_amdgcn_mfma_f32_16x16x16bf16_1k(vfl[ct][1], pb, o1b, 0, 0, 0);
      }
    }
    __builtin_amdgcn_s_setprio(0);
  }

  // ---- finalize: merge split accumulators, write ctx A-frags ----
  f32x4 o0 = o0a + o0b, o1 = o1a + o1b;
  lsum += __shfl_xor(lsum, 16);
  lsum += __shfl_xor(lsum, 32);
  float inv = 1.f / (lsum * 32.f);
  int rowg = b * SPAT + s;                  // rowg&15 == sig
  size_t tb = (((size_t)(rowg >> 4) * 8 + h) * 64 + sig) * 8 + (g & 1) * 4;
  size_t off0 = tb + (size_t)(g >> 1) * 128;        // d = 4g+r  (ktile=h)
  size_t off1 = tb + (size_t)(2 + (g >> 1)) * 128;  // d = 16+4g+r
  u16x4 hv0, lv0, hv1, lv1;
  #pragma unroll
  for (int r = 0; r < 4; ++r) {
    float x0 = o0[r] * inv;
    unsigned short h0 = f2bf(x0);
    hv0[r] = h0; lv0[r] = (unsigned short)f2bf(x0 - bf2f(h0));
    float x1 = o1[r] * inv;
    unsigned short h1 = f2bf(x1);
    hv1[r] = h1; lv1[r] = (unsigned short)f2bf(x1 - bf2f(h1));
  }
  *(u16x4*)(ctxfh + off0) = hv0;
  *(u16x4*)(ctxfl + off0) = lv0;
  *(u16x4*)(ctxfh + off1) = hv1;
  *(u16x4*)(ctxfl + off1) = lv1;
}

extern "C" void kernel_launch(void* const* d_in, const int* in_sizes, int n_in,
                              void* d_out, int out_size, void* d_ws, size_t ws_size,
                              hipStream_t stream) {
  const float* q  = (const float*)d_in[0];
  const float* k  = (const float*)d_in[1];
  const float* v  = (const float*)d_in[2];
  const float* Wq = (const float*)d_in[5];
  const float* bq = (const float*)d_in[6];
  const float* Wk = (const float*)d_in[7];
  const float* bk = (const float*)d_in[8];
  const float* Wv = (const float*)d_in[9];
  const float* bv = (const float*)d_in[10];
  const float* Wo = (const float*)d_in[11];
  const float* bo = (const float*)d_in[12];
  const float* Wp = (const float*)d_in[13];
  const float* bp = (const float*)d_in[14];
  const float* gk = (const float*)d_in[15];
  const float* sb = (const float*)d_in[16];
  float* out = (float*)d_out;

  const size_t NE = (size_t)BSZ * SPAT * DM;                 // 3276800
  char* ws = (char*)d_ws;
  int*   meta   = (int*)ws;                                  // 256 B
  float* logits = (float*)(ws + 256);                        // 12800 f32
  float* smooth = logits + BSZ * SPAT;                       // 12800 f32
  unsigned short* kcfh = (unsigned short*)(ws + 256 + 2 * BSZ * SPAT * 4);
  unsigned short* kcfl = kcfh + NE;
  unsigned short* vcfh = kcfl + NE;
  unsigned short* vcfl = vcfh + NE;
  unsigned short* qfh  = vcfl + NE;
  unsigned short* qfl  = qfh + NE;
  unsigned short* Qh   = qfl + NE;
  unsigned short* Ql   = Qh + NE;
  unsigned short* Kh   = Ql + NE;
  unsigned short* Kl   = Kh + NE;
  unsigned short* Vth  = Kl + NE;   // NOT aliased: QKV GEMMs fused in one
  unsigned short* Vtl  = Vth + NE;  // dispatch — z=0 reads qf while z=2 writes
  unsigned short* WTfh = Vtl + NE;                           // 4*65536 u16
  unsigned short* WTfl = WTfh + 4 * DM * DM;
  unsigned short* ctxfh = kcfh;     // alias kcf (dead after fused QKV GEMM)
  unsigned short* ctxfl = kcfl;

  prep_kernel<<<1632, 256, 0, stream>>>(q, Wq, Wk, Wv, Wo, qfh, qfl, WTfh, WTfl);
  logits_kernel<<<BSZ * SPAT / 4, 256, 0, stream>>>(k, Wp, bp, logits);
  entropy_kernel<<<BSZ, 512, 0, stream>>>(logits, gk, smooth);
  clsize_kernel<<<1, 512, 0, stream>>>(smooth, sb, meta);
  cluster_kernel<<<dim3(SPAT, BSZ), 256, 0, stream>>>(
      k, v, smooth, meta, kcfh, kcfl, vcfh, vcfl);
  mfma_gemm_qkv_kernel<<<dim3(200, 4, 3), 256, 0, stream>>>(
      qfh, qfl, kcfh, kcfl, vcfh, vcfl, WTfh, WTfl, bq, bk, bv,
      Qh, Ql, Kh, Kl, Vth, Vtl, meta);
  attn_mfma_kernel<<<dim3(25, BSZ, NH), 256, 0, stream>>>(
      Qh, Ql, Kh, Kl, Vth, Vtl, meta, ctxfh, ctxfl);
  mfma_gemm_o_kernel<<<dim3(200, 4), 256, 0, stream>>>(
      ctxfh, ctxfl, WTfh + 3 * DM * DM, WTfl + 3 * DM * DM, bo, out, meta);
}

// Round 16
// 120.796 us; speedup vs baseline: 1.1905x; 1.1905x over previous
//
#include <hip/hip_runtime.h>
#include <math.h>

#define SPAT 1600
#define BSZ 8
#define DM 256
#define NH 8
#define DH 32
#define NC16 100  // SPAT/16 c-tiles in K=16 V^T fragment layout

typedef __attribute__((ext_vector_type(8))) short bf16x8;
typedef __attribute__((ext_vector_type(4))) short bf16x4;
typedef __attribute__((ext_vector_type(4))) float f32x4;
typedef __attribute__((ext_vector_type(4))) unsigned short u16x4;

static __device__ __forceinline__ unsigned short f2bf(float x) {
  unsigned u = __float_as_uint(x);
  unsigned r = (u + 0x7fff + ((u >> 16) & 1)) >> 16;
  return (unsigned short)r;
}
static __device__ __forceinline__ float bf2f(unsigned short h) {
  return __uint_as_float(((unsigned)h) << 16);
}

// ---------------- K1: logits[b][s] = k[s][b][:] . Wp + bp ----------------
__global__ __launch_bounds__(256) void logits_kernel(
    const float* __restrict__ k, const float* __restrict__ Wp,
    const float* __restrict__ bp, float* __restrict__ logits)
{
  int wave = threadIdx.x >> 6, lane = threadIdx.x & 63;
  int idx = blockIdx.x * 4 + wave;           // 0..12799
  if (idx >= BSZ * SPAT) return;
  int b = idx / SPAT, s = idx - b * SPAT;
  const float4 kv = *(const float4*)(k + (s * BSZ + b) * DM + lane * 4);
  const float4 wv = *(const float4*)(Wp + lane * 4);
  float sum = kv.x * wv.x + kv.y * wv.y + kv.z * wv.z + kv.w * wv.w;
  #pragma unroll
  for (int off = 32; off; off >>= 1) sum += __shfl_xor(sum, off);
  if (lane == 0) logits[idx] = sum + bp[0];
}

// -------- K2: per-batch softmax -> entropy -> gaussian conv (512 thr) --------
__global__ __launch_bounds__(512) void entropy_kernel(
    const float* __restrict__ logits, const float* __restrict__ gk,
    float* __restrict__ smooth)
{
  int b = blockIdx.x;
  int t = threadIdx.x;
  const float* L = logits + b * SPAT;
  __shared__ float entpad[SPAT + 28];
  __shared__ float red[512];

  for (int i = t; i < SPAT + 28; i += 512) entpad[i] = 0.f;

  float m = -INFINITY;
  for (int i = t; i < SPAT; i += 512) m = fmaxf(m, L[i]);
  red[t] = m; __syncthreads();
  for (int o = 256; o; o >>= 1) { if (t < o) red[t] = fmaxf(red[t], red[t + o]); __syncthreads(); }
  m = red[0]; __syncthreads();

  float lsum = 0.f;
  for (int i = t; i < SPAT; i += 512) {
    float e = expf(L[i] - m);
    entpad[14 + i] = e;
    lsum += e;
  }
  red[t] = lsum; __syncthreads();
  for (int o = 256; o; o >>= 1) { if (t < o) red[t] += red[t + o]; __syncthreads(); }
  float S = red[0]; __syncthreads();

  for (int i = t; i < SPAT; i += 512) {
    float p = entpad[14 + i] / S + 1e-8f;
    entpad[14 + i] = -p * logf(p) / 0.6931471805599453f;
  }
  __syncthreads();

  for (int i = t; i < SPAT; i += 512) {
    float acc = 0.f;
    #pragma unroll
    for (int u = 0; u < 29; ++u) acc += entpad[i + u] * gk[28 - u];
    smooth[b * SPAT + i] = acc;
  }
}

// -------- K3: cluster size; wave w = batch w, shfl-reduce, no atomics --------
__global__ __launch_bounds__(512) void clsize_kernel(
    const float* __restrict__ smooth, const float* __restrict__ sobel,
    int* __restrict__ meta)
{
  __shared__ int cnts[8];
  int t = threadIdx.x;
  int w = t >> 6, lane = t & 63;
  float sb0 = sobel[0], sb1 = sobel[1], sb2 = sobel[2];
  const float* sm = smooth + w * SPAT;
  int local = 0;
  for (int i = 1 + lane; i < SPAT; i += 64) {
    float smL = (i >= 2) ? sm[i - 2] : 0.f;
    float a = sm[i - 1];
    float c = sm[i];
    float smR = (i + 1 < SPAT) ? sm[i + 1] : 0.f;
    float stepPrev = smL * sb2 + a * sb1 + c * sb0;
    float stepCur  = a * sb2 + c * sb1 + smR * sb0;
    local += ((stepPrev > 0.f) != (stepCur > 0.f));
  }
  #pragma unroll
  for (int off = 32; off; off >>= 1) local += __shfl_xor(local, off);
  if (lane == 0) cnts[w] = local;
  __syncthreads();
  if (t == 0) {
    float msum = 0.f;
    for (int b = 0; b < BSZ; ++b) msum += 1600.f / (float)(cnts[b] + 1);
    float mean = msum / 8.f;
    int C = (int)rintf(mean);
    if (C < 1) C = 1;
    int rem = SPAT % C;
    meta[0] = C; meta[1] = rem / 2; meta[2] = rem; meta[3] = (SPAT - rem) / C;
  }
}

// -------- K4: cluster pooling; serial per-thread softmax (no barriers),
// emits kc/vc as bf16 hi/lo A-fragments --------
__global__ __launch_bounds__(256) void cluster_kernel(
    const float* __restrict__ k, const float* __restrict__ v,
    const float* __restrict__ smooth, const int* __restrict__ meta,
    unsigned short* __restrict__ kcfh, unsigned short* __restrict__ kcfl,
    unsigned short* __restrict__ vcfh, unsigned short* __restrict__ vcfl)
{
  int c = blockIdx.x, b = blockIdx.y;
  int C = meta[0], lo = meta[1], n_cl = meta[3];
  if (c >= n_cl) return;
  const float* sm = smooth + b * SPAT + lo + c * C;

  // wave-uniform serial softmax over C (typically ~10) — zero barriers
  float m = sm[0];
  for (int j = 1; j < C; ++j) m = fmaxf(m, sm[j]);
  float S = 0.f;
  for (int j = 0; j < C; ++j) S += __expf(sm[j] - m);
  float invS = 1.f / S;

  int d = threadIdx.x;
  int s0 = lo + c * C;
  const float* kp = k + (s0 * BSZ + b) * DM + d;
  const float* vp = v + (s0 * BSZ + b) * DM + d;
  float ak = 0.f, av = 0.f;
  for (int j = 0; j < C; ++j) {
    float wj = __expf(sm[j] - m) * invS;
    ak += wj * kp[0];
    av += wj * vp[0];
    kp += BSZ * DM; vp += BSZ * DM;
  }
  int rowg = b * SPAT + c;
  size_t dst = (((size_t)(rowg >> 4) * 8 + (d >> 5)) * 64
                + ((d >> 3) & 3) * 16 + (rowg & 15)) * 8 + (d & 7);
  unsigned short hb = f2bf(ak);
  kcfh[dst] = hb; kcfl[dst] = (unsigned short)f2bf(ak - bf2f(hb));
  hb = f2bf(av);
  vcfh[dst] = hb; vcfl[dst] = (unsigned short)f2bf(av - bf2f(hb));
}

// -------- P0: fused prepw (W -> B-frags) + splitq (q -> A-frags) --------
__global__ __launch_bounds__(256) void prep_kernel(
    const float* __restrict__ q,
    const float* __restrict__ Wq, const float* __restrict__ Wk,
    const float* __restrict__ Wv, const float* __restrict__ Wo,
    unsigned short* __restrict__ qfh, unsigned short* __restrict__ qfl,
    unsigned short* __restrict__ WTh, unsigned short* __restrict__ WTl)
{
  int bx = blockIdx.x;
  if (bx < 1600) {
    // splitq: q (s,b,d) fp32 -> A-fragment-linear bf16 hi/lo
    int tg = bx * 256 + threadIdx.x;
    int row = tg >> 5;                       // b*1600+s
    int d0 = (tg & 31) * 8;
    int b = row / SPAT, s = row - b * SPAT;
    const float* src = q + (size_t)(s * BSZ + b) * DM + d0;
    float4 a = *(const float4*)src;
    float4 c = *(const float4*)(src + 4);
    float xs[8] = {a.x, a.y, a.z, a.w, c.x, c.y, c.z, c.w};
    bf16x8 hv, lv;
    #pragma unroll
    for (int j = 0; j < 8; ++j) {
      unsigned short hb = f2bf(xs[j]);
      hv[j] = (short)hb;
      lv[j] = (short)f2bf(xs[j] - bf2f(hb));
    }
    size_t dst = (((size_t)(row >> 4) * 8 + (d0 >> 5)) * 64
                  + ((d0 >> 3) & 3) * 16 + (row & 15)) * 8;
    *(bf16x8*)(qfh + dst) = hv;
    *(bf16x8*)(qfl + dst) = lv;
  } else {
    // prepw: W[k][n] -> B-frag elem (((mat*16+ntile)*8+ktile)*64+g*16+sig)*8+e
    int mb = bx - 1600;
    int mat = mb >> 3, ktile = mb & 7;
    const float* W = (mat == 0) ? Wq : (mat == 1) ? Wk : (mat == 2) ? Wv : Wo;
    int n = threadIdx.x;
    int ntile = n >> 4, sig = n & 15;
    size_t base = (((size_t)(mat * 16 + ntile) * 8 + ktile) * 64 + sig) * 8;
    #pragma unroll 4
    for (int i = 0; i < 32; ++i) {
      int kk = ktile * 32 + i;
      float x = W[kk * DM + n];
      unsigned short hb = f2bf(x);
      size_t dst = base + (size_t)(i >> 3) * 128 + (i & 7);
      WTh[dst] = hb;
      WTl[dst] = (unsigned short)f2bf(x - bf2f(hb));
    }
  }
}

// -------- shared GEMM body: fragment-linear operands, bf16x3 --------
// epi: 0 = bf16 hi/lo [bh][s|c][32]
//      1 = K=16 V^T A-frags [bh][c16][dhalf][lane][4]
//      2 = fp32 out[(s*8+b)*256+n]
static __device__ __forceinline__ void gemm_body(
    const unsigned short* __restrict__ Afh, const unsigned short* __restrict__ Afl,
    const unsigned short* __restrict__ Bfh, const unsigned short* __restrict__ Bfl,
    const float* __restrict__ bias,
    unsigned short* __restrict__ Oh, unsigned short* __restrict__ Ol,
    float* __restrict__ Of, int epi, int skipcl, const int* __restrict__ meta)
{
  int row0blk = blockIdx.x * 64;
  if (skipcl && (row0blk % SPAT) >= meta[3]) return;
  int wv = threadIdx.x >> 6, l = threadIdx.x & 63;
  int g = l >> 4, sig = l & 15;
  int row0 = row0blk + wv * 16;
  int rtile = row0 >> 4;
  int col0 = blockIdx.y * 64;
  int ntile0 = col0 >> 4;

  f32x4 acc[4] = {{0.f,0.f,0.f,0.f},{0.f,0.f,0.f,0.f},{0.f,0.f,0.f,0.f},{0.f,0.f,0.f,0.f}};

  #pragma unroll 1
  for (int kt = 0; kt < 8; ++kt) {
    size_t ao = (((size_t)rtile * 8 + kt) * 64 + l) * 8;
    bf16x8 ah = *(const bf16x8*)(Afh + ao);
    bf16x8 al = *(const bf16x8*)(Afl + ao);
    #pragma unroll
    for (int nt = 0; nt < 4; ++nt) {
      size_t bo = (((size_t)(ntile0 + nt) * 8 + kt) * 64 + l) * 8;
      bf16x8 bh = *(const bf16x8*)(Bfh + bo);
      bf16x8 bl = *(const bf16x8*)(Bfl + bo);
      acc[nt] = __builtin_amdgcn_mfma_f32_16x16x32_bf16(ah, bh, acc[nt], 0, 0, 0);
      acc[nt] = __builtin_amdgcn_mfma_f32_16x16x32_bf16(al, bh, acc[nt], 0, 0, 0);
      acc[nt] = __builtin_amdgcn_mfma_f32_16x16x32_bf16(ah, bl, acc[nt], 0, 0, 0);
    }
  }

  int bb = row0 / SPAT;
  int sbase = row0 - bb * SPAT + 4 * g;
  #pragma unroll
  for (int nt = 0; nt < 4; ++nt) {
    int n = col0 + nt * 16 + sig;
    float bi = bias[n];
    if (epi == 0) {
      int h = n >> 5, dl = n & 31;
      size_t base = (size_t)(bb * NH + h) * SPAT * DH + dl;
      #pragma unroll
      for (int r = 0; r < 4; ++r) {
        float x = acc[nt][r] + bi;
        unsigned short hb = f2bf(x);
        size_t dst = base + (size_t)(sbase + r) * DH;
        Oh[dst] = hb;
        Ol[dst] = (unsigned short)f2bf(x - bf2f(hb));
      }
    } else if (epi == 1) {
      // element: V[c = sbase+r][d = n] -> A-frag of 16x16x16 PV MFMA:
      // [bh][c>>4][(n&31)>>4][lane = ((c>>2)&3)*16 + (n&15)][c&3]
      int h = n >> 5;
      int bh = bb * NH + h;
      int dhalf = (n & 31) >> 4;
      int mrow = n & 15;
      #pragma unroll
      for (int r = 0; r < 4; ++r) {
        int c = sbase + r;
        float x = acc[nt][r] + bi;
        unsigned short hb = f2bf(x);
        size_t dst = ((((size_t)bh * NC16 + (c >> 4)) * 2 + dhalf) * 64
                      + ((c >> 2) & 3) * 16 + mrow) * 4 + (c & 3);
        Oh[dst] = hb;
        Ol[dst] = (unsigned short)f2bf(x - bf2f(hb));
      }
    } else {
      #pragma unroll
      for (int r = 0; r < 4; ++r) {
        float x = acc[nt][r] + bi;
        Of[(size_t)((sbase + r) * BSZ + bb) * DM + n] = x;
      }
    }
  }
}

// -------- K5a: fused Q/K/V projection GEMMs (blockIdx.z selects) --------
__global__ __launch_bounds__(256) void mfma_gemm_qkv_kernel(
    const unsigned short* __restrict__ qfh, const unsigned short* __restrict__ qfl,
    const unsigned short* __restrict__ kcfh, const unsigned short* __restrict__ kcfl,
    const unsigned short* __restrict__ vcfh, const unsigned short* __restrict__ vcfl,
    const unsigned short* __restrict__ WTfh, const unsigned short* __restrict__ WTfl,
    const float* __restrict__ bq, const float* __restrict__ bk, const float* __restrict__ bv,
    unsigned short* __restrict__ Qh, unsigned short* __restrict__ Ql,
    unsigned short* __restrict__ Kh, unsigned short* __restrict__ Kl,
    unsigned short* __restrict__ Vth, unsigned short* __restrict__ Vtl,
    const int* __restrict__ meta)
{
  int z = blockIdx.z;
  if (z == 0) {
    gemm_body(qfh, qfl, WTfh, WTfl, bq, Qh, Ql, nullptr, 0, 0, meta);
  } else if (z == 1) {
    gemm_body(kcfh, kcfl, WTfh + DM * DM, WTfl + DM * DM, bk, Kh, Kl, nullptr, 0, 1, meta);
  } else {
    gemm_body(vcfh, vcfl, WTfh + 2 * DM * DM, WTfl + 2 * DM * DM, bv, Vth, Vtl, nullptr, 1, 1, meta);
  }
}

// -------- K5b: output GEMM (epi=2, fp32 out + transpose) --------
__global__ __launch_bounds__(256) void mfma_gemm_o_kernel(
    const unsigned short* __restrict__ Afh, const unsigned short* __restrict__ Afl,
    const unsigned short* __restrict__ Bfh, const unsigned short* __restrict__ Bfl,
    const float* __restrict__ bias, float* __restrict__ Of,
    const int* __restrict__ meta)
{
  gemm_body(Afh, Afl, Bfh, Bfl, bias, nullptr, nullptr, Of, 2, 0, meta);
}

// -------- K6: MFMA attention (round-14 structure + chunk-order rotation).
// QK bf16x3 (16x16x32); PV K=16 fed directly from QK output regs.
// Rotation: wave w of block bx starts at chunk (w+bx)%nch and wraps —
// de-correlates the 4 waves' + 25 blocks' identical K/V access streams
// (round-14 PMC: all pipes <30%, eff BW ~1 TB/s -> correlated-miss
// latency-bound). Online softmax is order-invariant, so rotation is safe.
__global__ __launch_bounds__(256) void attn_mfma_kernel(
    const unsigned short* __restrict__ Qh, const unsigned short* __restrict__ Ql,
    const unsigned short* __restrict__ Kh, const unsigned short* __restrict__ Kl,
    const unsigned short* __restrict__ Vth, const unsigned short* __restrict__ Vtl,
    const int* __restrict__ meta,
    unsigned short* __restrict__ ctxfh, unsigned short* __restrict__ ctxfl)
{
  int b = blockIdx.y, h = blockIdx.z, bh = b * NH + h;
  int t = threadIdx.x;
  int w = t >> 6, l = t & 63;
  int g = l >> 4, sig = l & 15;
  int n_cl = meta[3];
  int s = blockIdx.x * 64 + w * 16 + sig;   // 25*64 = 1600

  size_t qoff = ((size_t)bh * SPAT + s) * DH + g * 8;
  bf16x8 qh = *(const bf16x8*)(Qh + qoff);
  bf16x8 ql = *(const bf16x8*)(Ql + qoff);

  const unsigned short* Kbh = Kh + (size_t)bh * SPAT * DH;
  const unsigned short* Kbl = Kl + (size_t)bh * SPAT * DH;
  const unsigned short* Vbh = Vth + (size_t)bh * NC16 * 2 * 64 * 4;
  const unsigned short* Vbl = Vtl + (size_t)bh * NC16 * 2 * 64 * 4;

  f32x4 o0 = {0.f, 0.f, 0.f, 0.f}, o1 = {0.f, 0.f, 0.f, 0.f};
  float m = -1e30f, lsum = 0.f;

  int nch = (n_cl + 63) >> 6;               // chunks of 64 clusters
  int start = (w + blockIdx.x) % nch;       // wave-uniform rotation

  for (int i = 0; i < nch; ++i) {
    int ci = i + start;
    if (ci >= nch) ci -= nch;
    int c0 = ci * 64;

    // ---- QK^T: rows cr = c0+ct*16+sig <= 1599 always (c0 <= 1536) ----
    f32x4 sc[4];
    __builtin_amdgcn_s_setprio(1);
    #pragma unroll
    for (int ct = 0; ct < 4; ++ct) {
      size_t ko = (size_t)(c0 + ct * 16 + sig) * DH + g * 8;
      bf16x8 kh = *(const bf16x8*)(Kbh + ko);
      bf16x8 kl = *(const bf16x8*)(Kbl + ko);
      f32x4 a = {0.f, 0.f, 0.f, 0.f};
      a = __builtin_amdgcn_mfma_f32_16x16x32_bf16(kh, qh, a, 0, 0, 0);
      a = __builtin_amdgcn_mfma_f32_16x16x32_bf16(kh, ql, a, 0, 0, 0);
      a = __builtin_amdgcn_mfma_f32_16x16x32_bf16(kl, qh, a, 0, 0, 0);
      sc[ct] = a;
    }
    __builtin_amdgcn_s_setprio(0);

    // ---- V A-frags for this chunk: issue BEFORE softmax (independent) ----
    bf16x4 vfh[4][2], vfl[4][2];
    #pragma unroll
    for (int ct = 0; ct < 4; ++ct) {
      int c16 = (c0 >> 4) + ct;             // <= 99, always in-buffer
      #pragma unroll
      for (int dh2 = 0; dh2 < 2; ++dh2) {
        size_t vo = (((size_t)c16 * 2 + dh2) * 64 + l) * 4;
        vfh[ct][dh2] = *(const bf16x4*)(Vbh + vo);
        vfl[ct][dh2] = *(const bf16x4*)(Vbl + vo);
      }
    }

    if (c0 + 64 > n_cl) {                   // tail chunk only: mask
      #pragma unroll
      for (int ct = 0; ct < 4; ++ct) {
        #pragma unroll
        for (int r = 0; r < 4; ++r) {
          int c = c0 + ct * 16 + g * 4 + r;
          if (c >= n_cl) sc[ct][r] = -INFINITY;
        }
      }
    }
    float mc = sc[0][0];
    #pragma unroll
    for (int ct = 0; ct < 4; ++ct) {
      #pragma unroll
      for (int r = 0; r < 4; ++r) mc = fmaxf(mc, sc[ct][r]);
    }
    mc = fmaxf(mc, __shfl_xor(mc, 16));
    mc = fmaxf(mc, __shfl_xor(mc, 32));
    float nm = fmaxf(m, mc);
    float corr = __expf(m - nm);
    m = nm;
    lsum *= corr; o0 *= corr; o1 *= corr;
    float ls0 = 0.f, ls1 = 0.f;
    #pragma unroll
    for (int ct = 0; ct < 4; ++ct) {
      #pragma unroll
      for (int r = 0; r < 4; ++r) {
        float p = __expf(sc[ct][r] - m);
        sc[ct][r] = p;
        if (ct < 2) ls0 += p; else ls1 += p;
      }
    }
    lsum += ls0 + ls1;

    // ---- PV: P already in B-frag layout for 16x16x16 (k = 4g+j) ----
    __builtin_amdgcn_s_setprio(1);
    #pragma unroll
    for (int ct = 0; ct < 4; ++ct) {
      if (c0 + ct * 16 >= n_cl) continue;   // wave-uniform skip
      bf16x4 pb;
      #pragma unroll
      for (int j = 0; j < 4; ++j) pb[j] = (short)f2bf(sc[ct][j]);
      o0 = __builtin_amdgcn_mfma_f32_16x16x16bf16_1k(vfh[ct][0], pb, o0, 0, 0, 0);
      o0 = __builtin_amdgcn_mfma_f32_16x16x16bf16_1k(vfl[ct][0], pb, o0, 0, 0, 0);
      o1 = __builtin_amdgcn_mfma_f32_16x16x16bf16_1k(vfh[ct][1], pb, o1, 0, 0, 0);
      o1 = __builtin_amdgcn_mfma_f32_16x16x16bf16_1k(vfl[ct][1], pb, o1, 0, 0, 0);
    }
    __builtin_amdgcn_s_setprio(0);
  }

  // ---- finalize: write O^T frags into ctx A-fragment layout ----
  lsum += __shfl_xor(lsum, 16);
  lsum += __shfl_xor(lsum, 32);
  float inv = 1.f / (lsum * 32.f);
  int rowg = b * SPAT + s;                  // rowg&15 == sig
  size_t tb = (((size_t)(rowg >> 4) * 8 + h) * 64 + sig) * 8 + (g & 1) * 4;
  size_t off0 = tb + (size_t)(g >> 1) * 128;        // d = 4g+r  (ktile=h)
  size_t off1 = tb + (size_t)(2 + (g >> 1)) * 128;  // d = 16+4g+r
  u16x4 hv0, lv0, hv1, lv1;
  #pragma unroll
  for (int r = 0; r < 4; ++r) {
    float x0 = o0[r] * inv;
    unsigned short h0 = f2bf(x0);
    hv0[r] = h0; lv0[r] = (unsigned short)f2bf(x0 - bf2f(h0));
    float x1 = o1[r] * inv;
    unsigned short h1 = f2bf(x1);
    hv1[r] = h1; lv1[r] = (unsigned short)f2bf(x1 - bf2f(h1));
  }
  *(u16x4*)(ctxfh + off0) = hv0;
  *(u16x4*)(ctxfl + off0) = lv0;
  *(u16x4*)(ctxfh + off1) = hv1;
  *(u16x4*)(ctxfl + off1) = lv1;
}

extern "C" void kernel_launch(void* const* d_in, const int* in_sizes, int n_in,
                              void* d_out, int out_size, void* d_ws, size_t ws_size,
                              hipStream_t stream) {
  const float* q  = (const float*)d_in[0];
  const float* k  = (const float*)d_in[1];
  const float* v  = (const float*)d_in[2];
  const float* Wq = (const float*)d_in[5];
  const float* bq = (const float*)d_in[6];
  const float* Wk = (const float*)d_in[7];
  const float* bk = (const float*)d_in[8];
  const float* Wv = (const float*)d_in[9];
  const float* bv = (const float*)d_in[10];
  const float* Wo = (const float*)d_in[11];
  const float* bo = (const float*)d_in[12];
  const float* Wp = (const float*)d_in[13];
  const float* bp = (const float*)d_in[14];
  const float* gk = (const float*)d_in[15];
  const float* sb = (const float*)d_in[16];
  float* out = (float*)d_out;

  const size_t NE = (size_t)BSZ * SPAT * DM;                 // 3276800
  char* ws = (char*)d_ws;
  int*   meta   = (int*)ws;                                  // 256 B
  float* logits = (float*)(ws + 256);                        // 12800 f32
  float* smooth = logits + BSZ * SPAT;                       // 12800 f32
  unsigned short* kcfh = (unsigned short*)(ws + 256 + 2 * BSZ * SPAT * 4);
  unsigned short* kcfl = kcfh + NE;
  unsigned short* vcfh = kcfl + NE;
  unsigned short* vcfl = vcfh + NE;
  unsigned short* qfh  = vcfl + NE;
  unsigned short* qfl  = qfh + NE;
  unsigned short* Qh   = qfl + NE;
  unsigned short* Ql   = Qh + NE;
  unsigned short* Kh   = Ql + NE;
  unsigned short* Kl   = Kh + NE;
  unsigned short* Vth  = Kl + NE;   // NOT aliased: QKV GEMMs fused in one
  unsigned short* Vtl  = Vth + NE;  // dispatch — z=0 reads qf while z=2 writes
  unsigned short* WTfh = Vtl + NE;                           // 4*65536 u16
  unsigned short* WTfl = WTfh + 4 * DM * DM;
  unsigned short* ctxfh = kcfh;     // alias kcf (dead after fused QKV GEMM)
  unsigned short* ctxfl = kcfl;

  prep_kernel<<<1632, 256, 0, stream>>>(q, Wq, Wk, Wv, Wo, qfh, qfl, WTfh, WTfl);
  logits_kernel<<<BSZ * SPAT / 4, 256, 0, stream>>>(k, Wp, bp, logits);
  entropy_kernel<<<BSZ, 512, 0, stream>>>(logits, gk, smooth);
  clsize_kernel<<<1, 512, 0, stream>>>(smooth, sb, meta);
  cluster_kernel<<<dim3(SPAT, BSZ), 256, 0, stream>>>(
      k, v, smooth, meta, kcfh, kcfl, vcfh, vcfl);
  mfma_gemm_qkv_kernel<<<dim3(200, 4, 3), 256, 0, stream>>>(
      qfh, qfl, kcfh, kcfl, vcfh, vcfl, WTfh, WTfl, bq, bk, bv,
      Qh, Ql, Kh, Kl, Vth, Vtl, meta);
  attn_mfma_kernel<<<dim3(25, BSZ, NH), 256, 0, stream>>>(
      Qh, Ql, Kh, Kl, Vth, Vtl, meta, ctxfh, ctxfl);
  mfma_gemm_o_kernel<<<dim3(200, 4), 256, 0, stream>>>(
      ctxfh, ctxfl, WTfh + 3 * DM * DM, WTfl + 3 * DM * DM, bo, out, meta);
}

// Round 17
// 118.803 us; speedup vs baseline: 1.2105x; 1.0168x over previous
//
#include <hip/hip_runtime.h>
#include <math.h>

#define SPAT 1600
#define BSZ 8
#define DM 256
#define NH 8
#define DH 32
#define NC16 100  // SPAT/16 c-tiles in K=16 V^T fragment layout

typedef __attribute__((ext_vector_type(8))) short bf16x8;
typedef __attribute__((ext_vector_type(4))) short bf16x4;
typedef __attribute__((ext_vector_type(4))) float f32x4;
typedef __attribute__((ext_vector_type(4))) unsigned short u16x4;

static __device__ __forceinline__ unsigned short f2bf(float x) {
  unsigned u = __float_as_uint(x);
  unsigned r = (u + 0x7fff + ((u >> 16) & 1)) >> 16;
  return (unsigned short)r;
}
static __device__ __forceinline__ float bf2f(unsigned short h) {
  return __uint_as_float(((unsigned)h) << 16);
}

// ---------------- K1: logits[b][s] = k[s][b][:] . Wp + bp ----------------
__global__ __launch_bounds__(256) void logits_kernel(
    const float* __restrict__ k, const float* __restrict__ Wp,
    const float* __restrict__ bp, float* __restrict__ logits)
{
  int wave = threadIdx.x >> 6, lane = threadIdx.x & 63;
  int idx = blockIdx.x * 4 + wave;           // 0..12799
  if (idx >= BSZ * SPAT) return;
  int b = idx / SPAT, s = idx - b * SPAT;
  const float4 kv = *(const float4*)(k + (s * BSZ + b) * DM + lane * 4);
  const float4 wv = *(const float4*)(Wp + lane * 4);
  float sum = kv.x * wv.x + kv.y * wv.y + kv.z * wv.z + kv.w * wv.w;
  #pragma unroll
  for (int off = 32; off; off >>= 1) sum += __shfl_xor(sum, off);
  if (lane == 0) logits[idx] = sum + bp[0];
}

// -------- K2: per-batch softmax -> entropy -> gaussian conv (512 thr) --------
__global__ __launch_bounds__(512) void entropy_kernel(
    const float* __restrict__ logits, const float* __restrict__ gk,
    float* __restrict__ smooth)
{
  int b = blockIdx.x;
  int t = threadIdx.x;
  const float* L = logits + b * SPAT;
  __shared__ float entpad[SPAT + 28];
  __shared__ float red[512];

  for (int i = t; i < SPAT + 28; i += 512) entpad[i] = 0.f;

  float m = -INFINITY;
  for (int i = t; i < SPAT; i += 512) m = fmaxf(m, L[i]);
  red[t] = m; __syncthreads();
  for (int o = 256; o; o >>= 1) { if (t < o) red[t] = fmaxf(red[t], red[t + o]); __syncthreads(); }
  m = red[0]; __syncthreads();

  float lsum = 0.f;
  for (int i = t; i < SPAT; i += 512) {
    float e = expf(L[i] - m);
    entpad[14 + i] = e;
    lsum += e;
  }
  red[t] = lsum; __syncthreads();
  for (int o = 256; o; o >>= 1) { if (t < o) red[t] += red[t + o]; __syncthreads(); }
  float S = red[0]; __syncthreads();

  for (int i = t; i < SPAT; i += 512) {
    float p = entpad[14 + i] / S + 1e-8f;
    entpad[14 + i] = -p * logf(p) / 0.6931471805599453f;
  }
  __syncthreads();

  for (int i = t; i < SPAT; i += 512) {
    float acc = 0.f;
    #pragma unroll
    for (int u = 0; u < 29; ++u) acc += entpad[i + u] * gk[28 - u];
    smooth[b * SPAT + i] = acc;
  }
}

// -------- K3: cluster size; wave w = batch w, shfl-reduce, no atomics --------
__global__ __launch_bounds__(512) void clsize_kernel(
    const float* __restrict__ smooth, const float* __restrict__ sobel,
    int* __restrict__ meta)
{
  __shared__ int cnts[8];
  int t = threadIdx.x;
  int w = t >> 6, lane = t & 63;
  float sb0 = sobel[0], sb1 = sobel[1], sb2 = sobel[2];
  const float* sm = smooth + w * SPAT;
  int local = 0;
  for (int i = 1 + lane; i < SPAT; i += 64) {
    float smL = (i >= 2) ? sm[i - 2] : 0.f;
    float a = sm[i - 1];
    float c = sm[i];
    float smR = (i + 1 < SPAT) ? sm[i + 1] : 0.f;
    float stepPrev = smL * sb2 + a * sb1 + c * sb0;
    float stepCur  = a * sb2 + c * sb1 + smR * sb0;
    local += ((stepPrev > 0.f) != (stepCur > 0.f));
  }
  #pragma unroll
  for (int off = 32; off; off >>= 1) local += __shfl_xor(local, off);
  if (lane == 0) cnts[w] = local;
  __syncthreads();
  if (t == 0) {
    float msum = 0.f;
    for (int b = 0; b < BSZ; ++b) msum += 1600.f / (float)(cnts[b] + 1);
    float mean = msum / 8.f;
    int C = (int)rintf(mean);
    if (C < 1) C = 1;
    int rem = SPAT % C;
    meta[0] = C; meta[1] = rem / 2; meta[2] = rem; meta[3] = (SPAT - rem) / C;
  }
}

// -------- K4: cluster pooling; serial per-thread softmax (no barriers),
// emits kc/vc as bf16 hi/lo A-fragments --------
__global__ __launch_bounds__(256) void cluster_kernel(
    const float* __restrict__ k, const float* __restrict__ v,
    const float* __restrict__ smooth, const int* __restrict__ meta,
    unsigned short* __restrict__ kcfh, unsigned short* __restrict__ kcfl,
    unsigned short* __restrict__ vcfh, unsigned short* __restrict__ vcfl)
{
  int c = blockIdx.x, b = blockIdx.y;
  int C = meta[0], lo = meta[1], n_cl = meta[3];
  if (c >= n_cl) return;
  const float* sm = smooth + b * SPAT + lo + c * C;

  // wave-uniform serial softmax over C (typically ~10) — zero barriers
  float m = sm[0];
  for (int j = 1; j < C; ++j) m = fmaxf(m, sm[j]);
  float S = 0.f;
  for (int j = 0; j < C; ++j) S += __expf(sm[j] - m);
  float invS = 1.f / S;

  int d = threadIdx.x;
  int s0 = lo + c * C;
  const float* kp = k + (s0 * BSZ + b) * DM + d;
  const float* vp = v + (s0 * BSZ + b) * DM + d;
  float ak = 0.f, av = 0.f;
  for (int j = 0; j < C; ++j) {
    float wj = __expf(sm[j] - m) * invS;
    ak += wj * kp[0];
    av += wj * vp[0];
    kp += BSZ * DM; vp += BSZ * DM;
  }
  int rowg = b * SPAT + c;
  size_t dst = (((size_t)(rowg >> 4) * 8 + (d >> 5)) * 64
                + ((d >> 3) & 3) * 16 + (rowg & 15)) * 8 + (d & 7);
  unsigned short hb = f2bf(ak);
  kcfh[dst] = hb; kcfl[dst] = (unsigned short)f2bf(ak - bf2f(hb));
  hb = f2bf(av);
  vcfh[dst] = hb; vcfl[dst] = (unsigned short)f2bf(av - bf2f(hb));
}

// -------- P0: fused prepw (W -> B-frags) + splitq (q -> A-frags) --------
__global__ __launch_bounds__(256) void prep_kernel(
    const float* __restrict__ q,
    const float* __restrict__ Wq, const float* __restrict__ Wk,
    const float* __restrict__ Wv, const float* __restrict__ Wo,
    unsigned short* __restrict__ qfh, unsigned short* __restrict__ qfl,
    unsigned short* __restrict__ WTh, unsigned short* __restrict__ WTl)
{
  int bx = blockIdx.x;
  if (bx < 1600) {
    // splitq: q (s,b,d) fp32 -> A-fragment-linear bf16 hi/lo
    int tg = bx * 256 + threadIdx.x;
    int row = tg >> 5;                       // b*1600+s
    int d0 = (tg & 31) * 8;
    int b = row / SPAT, s = row - b * SPAT;
    const float* src = q + (size_t)(s * BSZ + b) * DM + d0;
    float4 a = *(const float4*)src;
    float4 c = *(const float4*)(src + 4);
    float xs[8] = {a.x, a.y, a.z, a.w, c.x, c.y, c.z, c.w};
    bf16x8 hv, lv;
    #pragma unroll
    for (int j = 0; j < 8; ++j) {
      unsigned short hb = f2bf(xs[j]);
      hv[j] = (short)hb;
      lv[j] = (short)f2bf(xs[j] - bf2f(hb));
    }
    size_t dst = (((size_t)(row >> 4) * 8 + (d0 >> 5)) * 64
                  + ((d0 >> 3) & 3) * 16 + (row & 15)) * 8;
    *(bf16x8*)(qfh + dst) = hv;
    *(bf16x8*)(qfl + dst) = lv;
  } else {
    // prepw: W[k][n] -> B-frag elem (((mat*16+ntile)*8+ktile)*64+g*16+sig)*8+e
    int mb = bx - 1600;
    int mat = mb >> 3, ktile = mb & 7;
    const float* W = (mat == 0) ? Wq : (mat == 1) ? Wk : (mat == 2) ? Wv : Wo;
    int n = threadIdx.x;
    int ntile = n >> 4, sig = n & 15;
    size_t base = (((size_t)(mat * 16 + ntile) * 8 + ktile) * 64 + sig) * 8;
    #pragma unroll 4
    for (int i = 0; i < 32; ++i) {
      int kk = ktile * 32 + i;
      float x = W[kk * DM + n];
      unsigned short hb = f2bf(x);
      size_t dst = base + (size_t)(i >> 3) * 128 + (i & 7);
      WTh[dst] = hb;
      WTl[dst] = (unsigned short)f2bf(x - bf2f(hb));
    }
  }
}

// -------- shared GEMM body: fragment-linear operands, bf16x3 --------
// epi: 0 = bf16 hi/lo [bh][s|c][32]
//      1 = K=16 V^T A-frags [bh][c16][dhalf][lane][4]
//      2 = fp32 out[(s*8+b)*256+n]
static __device__ __forceinline__ void gemm_body(
    const unsigned short* __restrict__ Afh, const unsigned short* __restrict__ Afl,
    const unsigned short* __restrict__ Bfh, const unsigned short* __restrict__ Bfl,
    const float* __restrict__ bias,
    unsigned short* __restrict__ Oh, unsigned short* __restrict__ Ol,
    float* __restrict__ Of, int epi, int skipcl, const int* __restrict__ meta)
{
  int row0blk = blockIdx.x * 64;
  if (skipcl && (row0blk % SPAT) >= meta[3]) return;
  int wv = threadIdx.x >> 6, l = threadIdx.x & 63;
  int g = l >> 4, sig = l & 15;
  int row0 = row0blk + wv * 16;
  int rtile = row0 >> 4;
  int col0 = blockIdx.y * 64;
  int ntile0 = col0 >> 4;

  f32x4 acc[4] = {{0.f,0.f,0.f,0.f},{0.f,0.f,0.f,0.f},{0.f,0.f,0.f,0.f},{0.f,0.f,0.f,0.f}};

  #pragma unroll 1
  for (int kt = 0; kt < 8; ++kt) {
    size_t ao = (((size_t)rtile * 8 + kt) * 64 + l) * 8;
    bf16x8 ah = *(const bf16x8*)(Afh + ao);
    bf16x8 al = *(const bf16x8*)(Afl + ao);
    #pragma unroll
    for (int nt = 0; nt < 4; ++nt) {
      size_t bo = (((size_t)(ntile0 + nt) * 8 + kt) * 64 + l) * 8;
      bf16x8 bh = *(const bf16x8*)(Bfh + bo);
      bf16x8 bl = *(const bf16x8*)(Bfl + bo);
      acc[nt] = __builtin_amdgcn_mfma_f32_16x16x32_bf16(ah, bh, acc[nt], 0, 0, 0);
      acc[nt] = __builtin_amdgcn_mfma_f32_16x16x32_bf16(al, bh, acc[nt], 0, 0, 0);
      acc[nt] = __builtin_amdgcn_mfma_f32_16x16x32_bf16(ah, bl, acc[nt], 0, 0, 0);
    }
  }

  int bb = row0 / SPAT;
  int sbase = row0 - bb * SPAT + 4 * g;
  #pragma unroll
  for (int nt = 0; nt < 4; ++nt) {
    int n = col0 + nt * 16 + sig;
    float bi = bias[n];
    if (epi == 0) {
      int h = n >> 5, dl = n & 31;
      size_t base = (size_t)(bb * NH + h) * SPAT * DH + dl;
      #pragma unroll
      for (int r = 0; r < 4; ++r) {
        float x = acc[nt][r] + bi;
        unsigned short hb = f2bf(x);
        size_t dst = base + (size_t)(sbase + r) * DH;
        Oh[dst] = hb;
        Ol[dst] = (unsigned short)f2bf(x - bf2f(hb));
      }
    } else if (epi == 1) {
      // element: V[c = sbase+r][d = n] -> A-frag of 16x16x16 PV MFMA:
      // [bh][c>>4][(n&31)>>4][lane = ((c>>2)&3)*16 + (n&15)][c&3]
      int h = n >> 5;
      int bh = bb * NH + h;
      int dhalf = (n & 31) >> 4;
      int mrow = n & 15;
      #pragma unroll
      for (int r = 0; r < 4; ++r) {
        int c = sbase + r;
        float x = acc[nt][r] + bi;
        unsigned short hb = f2bf(x);
        size_t dst = ((((size_t)bh * NC16 + (c >> 4)) * 2 + dhalf) * 64
                      + ((c >> 2) & 3) * 16 + mrow) * 4 + (c & 3);
        Oh[dst] = hb;
        Ol[dst] = (unsigned short)f2bf(x - bf2f(hb));
      }
    } else {
      #pragma unroll
      for (int r = 0; r < 4; ++r) {
        float x = acc[nt][r] + bi;
        Of[(size_t)((sbase + r) * BSZ + bb) * DM + n] = x;
      }
    }
  }
}

// -------- K5a: fused Q/K/V projection GEMMs (blockIdx.z selects) --------
__global__ __launch_bounds__(256) void mfma_gemm_qkv_kernel(
    const unsigned short* __restrict__ qfh, const unsigned short* __restrict__ qfl,
    const unsigned short* __restrict__ kcfh, const unsigned short* __restrict__ kcfl,
    const unsigned short* __restrict__ vcfh, const unsigned short* __restrict__ vcfl,
    const unsigned short* __restrict__ WTfh, const unsigned short* __restrict__ WTfl,
    const float* __restrict__ bq, const float* __restrict__ bk, const float* __restrict__ bv,
    unsigned short* __restrict__ Qh, unsigned short* __restrict__ Ql,
    unsigned short* __restrict__ Kh, unsigned short* __restrict__ Kl,
    unsigned short* __restrict__ Vth, unsigned short* __restrict__ Vtl,
    const int* __restrict__ meta)
{
  int z = blockIdx.z;
  if (z == 0) {
    gemm_body(qfh, qfl, WTfh, WTfl, bq, Qh, Ql, nullptr, 0, 0, meta);
  } else if (z == 1) {
    gemm_body(kcfh, kcfl, WTfh + DM * DM, WTfl + DM * DM, bk, Kh, Kl, nullptr, 0, 1, meta);
  } else {
    gemm_body(vcfh, vcfl, WTfh + 2 * DM * DM, WTfl + 2 * DM * DM, bv, Vth, Vtl, nullptr, 1, 1, meta);
  }
}

// -------- K5b: output GEMM (epi=2, fp32 out + transpose) --------
__global__ __launch_bounds__(256) void mfma_gemm_o_kernel(
    const unsigned short* __restrict__ Afh, const unsigned short* __restrict__ Afl,
    const unsigned short* __restrict__ Bfh, const unsigned short* __restrict__ Bfl,
    const float* __restrict__ bias, float* __restrict__ Of,
    const int* __restrict__ meta)
{
  gemm_body(Afh, Afl, Bfh, Bfl, bias, nullptr, nullptr, Of, 2, 0, meta);
}

// -------- K6: MFMA attention (round-14 structure, XCD-pinned grid).
// Grid swapped to (bh=64, sblk=25): linear block id = bh + 64*sblk, XCD =
// id % 8 = bh % 8 -> all 25 s-blocks of one (b,h) land on ONE XCD, whose
// 8 bh working sets (8 x 410 KB = 3.3 MB) fit its 4 MiB L2. Round-16 PMC
// showed the (25,8,8) grid thrashes: each XCD touched all 64 bh sets
// (26 MB >> L2). QK bf16x3; PV K=16 fed directly from QK output regs.
__global__ __launch_bounds__(256) void attn_mfma_kernel(
    const unsigned short* __restrict__ Qh, const unsigned short* __restrict__ Ql,
    const unsigned short* __restrict__ Kh, const unsigned short* __restrict__ Kl,
    const unsigned short* __restrict__ Vth, const unsigned short* __restrict__ Vtl,
    const int* __restrict__ meta,
    unsigned short* __restrict__ ctxfh, unsigned short* __restrict__ ctxfl)
{
  int bh = blockIdx.x;                      // 0..63 -> XCD = bh % 8
  int b = bh >> 3, h = bh & 7;
  int t = threadIdx.x;
  int w = t >> 6, l = t & 63;
  int g = l >> 4, sig = l & 15;
  int n_cl = meta[3];
  int s = blockIdx.y * 64 + w * 16 + sig;   // 25*64 = 1600

  size_t qoff = ((size_t)bh * SPAT + s) * DH + g * 8;
  bf16x8 qh = *(const bf16x8*)(Qh + qoff);
  bf16x8 ql = *(const bf16x8*)(Ql + qoff);

  const unsigned short* Kbh = Kh + (size_t)bh * SPAT * DH;
  const unsigned short* Kbl = Kl + (size_t)bh * SPAT * DH;
  const unsigned short* Vbh = Vth + (size_t)bh * NC16 * 2 * 64 * 4;
  const unsigned short* Vbl = Vtl + (size_t)bh * NC16 * 2 * 64 * 4;

  f32x4 o0 = {0.f, 0.f, 0.f, 0.f}, o1 = {0.f, 0.f, 0.f, 0.f};
  float m = -1e30f, lsum = 0.f;

  for (int c0 = 0; c0 < n_cl; c0 += 64) {
    // ---- QK^T: rows cr = c0+ct*16+sig <= 1599 always (c0 <= 1536) ----
    f32x4 sc[4];
    __builtin_amdgcn_s_setprio(1);
    #pragma unroll
    for (int ct = 0; ct < 4; ++ct) {
      size_t ko = (size_t)(c0 + ct * 16 + sig) * DH + g * 8;
      bf16x8 kh = *(const bf16x8*)(Kbh + ko);
      bf16x8 kl = *(const bf16x8*)(Kbl + ko);
      f32x4 a = {0.f, 0.f, 0.f, 0.f};
      a = __builtin_amdgcn_mfma_f32_16x16x32_bf16(kh, qh, a, 0, 0, 0);
      a = __builtin_amdgcn_mfma_f32_16x16x32_bf16(kh, ql, a, 0, 0, 0);
      a = __builtin_amdgcn_mfma_f32_16x16x32_bf16(kl, qh, a, 0, 0, 0);
      sc[ct] = a;
    }
    __builtin_amdgcn_s_setprio(0);

    // ---- V A-frags for this chunk: issue BEFORE softmax (independent) ----
    bf16x4 vfh[4][2], vfl[4][2];
    #pragma unroll
    for (int ct = 0; ct < 4; ++ct) {
      int c16 = (c0 >> 4) + ct;             // <= 99, always in-buffer
      #pragma unroll
      for (int dh2 = 0; dh2 < 2; ++dh2) {
        size_t vo = (((size_t)c16 * 2 + dh2) * 64 + l) * 4;
        vfh[ct][dh2] = *(const bf16x4*)(Vbh + vo);
        vfl[ct][dh2] = *(const bf16x4*)(Vbl + vo);
      }
    }

    if (c0 + 64 > n_cl) {                   // tail chunk only: mask
      #pragma unroll
      for (int ct = 0; ct < 4; ++ct) {
        #pragma unroll
        for (int r = 0; r < 4; ++r) {
          int c = c0 + ct * 16 + g * 4 + r;
          if (c >= n_cl) sc[ct][r] = -INFINITY;
        }
      }
    }
    float mc = sc[0][0];
    #pragma unroll
    for (int ct = 0; ct < 4; ++ct) {
      #pragma unroll
      for (int r = 0; r < 4; ++r) mc = fmaxf(mc, sc[ct][r]);
    }
    mc = fmaxf(mc, __shfl_xor(mc, 16));
    mc = fmaxf(mc, __shfl_xor(mc, 32));
    float nm = fmaxf(m, mc);
    float corr = __expf(m - nm);
    m = nm;
    lsum *= corr; o0 *= corr; o1 *= corr;
    float ls0 = 0.f, ls1 = 0.f;
    #pragma unroll
    for (int ct = 0; ct < 4; ++ct) {
      #pragma unroll
      for (int r = 0; r < 4; ++r) {
        float p = __expf(sc[ct][r] - m);
        sc[ct][r] = p;
        if (ct < 2) ls0 += p; else ls1 += p;
      }
    }
    lsum += ls0 + ls1;

    // ---- PV: P already in B-frag layout for 16x16x16 (k = 4g+j) ----
    __builtin_amdgcn_s_setprio(1);
    #pragma unroll
    for (int ct = 0; ct < 4; ++ct) {
      if (c0 + ct * 16 >= n_cl) continue;   // wave-uniform skip
      bf16x4 pb;
      #pragma unroll
      for (int j = 0; j < 4; ++j) pb[j] = (short)f2bf(sc[ct][j]);
      o0 = __builtin_amdgcn_mfma_f32_16x16x16bf16_1k(vfh[ct][0], pb, o0, 0, 0, 0);
      o0 = __builtin_amdgcn_mfma_f32_16x16x16bf16_1k(vfl[ct][0], pb, o0, 0, 0, 0);
      o1 = __builtin_amdgcn_mfma_f32_16x16x16bf16_1k(vfh[ct][1], pb, o1, 0, 0, 0);
      o1 = __builtin_amdgcn_mfma_f32_16x16x16bf16_1k(vfl[ct][1], pb, o1, 0, 0, 0);
    }
    __builtin_amdgcn_s_setprio(0);
  }

  // ---- finalize: write O^T frags into ctx A-fragment layout ----
  lsum += __shfl_xor(lsum, 16);
  lsum += __shfl_xor(lsum, 32);
  float inv = 1.f / (lsum * 32.f);
  int rowg = b * SPAT + s;                  // rowg&15 == sig
  size_t tb = (((size_t)(rowg >> 4) * 8 + h) * 64 + sig) * 8 + (g & 1) * 4;
  size_t off0 = tb + (size_t)(g >> 1) * 128;        // d = 4g+r  (ktile=h)
  size_t off1 = tb + (size_t)(2 + (g >> 1)) * 128;  // d = 16+4g+r
  u16x4 hv0, lv0, hv1, lv1;
  #pragma unroll
  for (int r = 0; r < 4; ++r) {
    float x0 = o0[r] * inv;
    unsigned short h0 = f2bf(x0);
    hv0[r] = h0; lv0[r] = (unsigned short)f2bf(x0 - bf2f(h0));
    float x1 = o1[r] * inv;
    unsigned short h1 = f2bf(x1);
    hv1[r] = h1; lv1[r] = (unsigned short)f2bf(x1 - bf2f(h1));
  }
  *(u16x4*)(ctxfh + off0) = hv0;
  *(u16x4*)(ctxfl + off0) = lv0;
  *(u16x4*)(ctxfh + off1) = hv1;
  *(u16x4*)(ctxfl + off1) = lv1;
}

extern "C" void kernel_launch(void* const* d_in, const int* in_sizes, int n_in,
                              void* d_out, int out_size, void* d_ws, size_t ws_size,
                              hipStream_t stream) {
  const float* q  = (const float*)d_in[0];
  const float* k  = (const float*)d_in[1];
  const float* v  = (const float*)d_in[2];
  const float* Wq = (const float*)d_in[5];
  const float* bq = (const float*)d_in[6];
  const float* Wk = (const float*)d_in[7];
  const float* bk = (const float*)d_in[8];
  const float* Wv = (const float*)d_in[9];
  const float* bv = (const float*)d_in[10];
  const float* Wo = (const float*)d_in[11];
  const float* bo = (const float*)d_in[12];
  const float* Wp = (const float*)d_in[13];
  const float* bp = (const float*)d_in[14];
  const float* gk = (const float*)d_in[15];
  const float* sb = (const float*)d_in[16];
  float* out = (float*)d_out;

  const size_t NE = (size_t)BSZ * SPAT * DM;                 // 3276800
  char* ws = (char*)d_ws;
  int*   meta   = (int*)ws;                                  // 256 B
  float* logits = (float*)(ws + 256);                        // 12800 f32
  float* smooth = logits + BSZ * SPAT;                       // 12800 f32
  unsigned short* kcfh = (unsigned short*)(ws + 256 + 2 * BSZ * SPAT * 4);
  unsigned short* kcfl = kcfh + NE;
  unsigned short* vcfh = kcfl + NE;
  unsigned short* vcfl = vcfh + NE;
  unsigned short* qfh  = vcfl + NE;
  unsigned short* qfl  = qfh + NE;
  unsigned short* Qh   = qfl + NE;
  unsigned short* Ql   = Qh + NE;
  unsigned short* Kh   = Ql + NE;
  unsigned short* Kl   = Kh + NE;
  unsigned short* Vth  = Kl + NE;   // NOT aliased: QKV GEMMs fused in one
  unsigned short* Vtl  = Vth + NE;  // dispatch — z=0 reads qf while z=2 writes
  unsigned short* WTfh = Vtl + NE;                           // 4*65536 u16
  unsigned short* WTfl = WTfh + 4 * DM * DM;
  unsigned short* ctxfh = kcfh;     // alias kcf (dead after fused QKV GEMM)
  unsigned short* ctxfl = kcfl;

  prep_kernel<<<1632, 256, 0, stream>>>(q, Wq, Wk, Wv, Wo, qfh, qfl, WTfh, WTfl);
  logits_kernel<<<BSZ * SPAT / 4, 256, 0, stream>>>(k, Wp, bp, logits);
  entropy_kernel<<<BSZ, 512, 0, stream>>>(logits, gk, smooth);
  clsize_kernel<<<1, 512, 0, stream>>>(smooth, sb, meta);
  cluster_kernel<<<dim3(SPAT, BSZ), 256, 0, stream>>>(
      k, v, smooth, meta, kcfh, kcfl, vcfh, vcfl);
  mfma_gemm_qkv_kernel<<<dim3(200, 4, 3), 256, 0, stream>>>(
      qfh, qfl, kcfh, kcfl, vcfh, vcfl, WTfh, WTfl, bq, bk, bv,
      Qh, Ql, Kh, Kl, Vth, Vtl, meta);
  attn_mfma_kernel<<<dim3(64, 25), 256, 0, stream>>>(
      Qh, Ql, Kh, Kl, Vth, Vtl, meta, ctxfh, ctxfl);
  mfma_gemm_o_kernel<<<dim3(200, 4), 256, 0, stream>>>(
      ctxfh, ctxfl, WTfh + 3 * DM * DM, WTfl + 3 * DM * DM, bo, out, meta);
}

// Round 18
// 115.950 us; speedup vs baseline: 1.2402x; 1.0246x over previous
//
#include <hip/hip_runtime.h>
#include <math.h>

#define SPAT 1600
#define BSZ 8
#define DM 256
#define NH 8
#define DH 32
#define NC16 100  // SPAT/16 c-tiles in K=16 V^T fragment layout

typedef __attribute__((ext_vector_type(8))) short bf16x8;
typedef __attribute__((ext_vector_type(4))) short bf16x4;
typedef __attribute__((ext_vector_type(4))) float f32x4;
typedef __attribute__((ext_vector_type(4))) unsigned short u16x4;

static __device__ __forceinline__ unsigned short f2bf(float x) {
  unsigned u = __float_as_uint(x);
  unsigned r = (u + 0x7fff + ((u >> 16) & 1)) >> 16;
  return (unsigned short)r;
}
static __device__ __forceinline__ float bf2f(unsigned short h) {
  return __uint_as_float(((unsigned)h) << 16);
}

// -------- K1/P0 fused: logits + splitq + prepw (independent inputs) --------
// bx < 3200: logits[b][s] = k[s][b][:] . Wp + bp   (4 rows/block)
// 3200 <= bx < 4800: q (s,b,d) fp32 -> A-frag bf16 hi/lo
// bx >= 4800: W[k][n] -> B-frag bf16 hi/lo (32 blocks)
__global__ __launch_bounds__(256) void prep_logits_kernel(
    const float* __restrict__ k, const float* __restrict__ Wp,
    const float* __restrict__ bp, float* __restrict__ logits,
    const float* __restrict__ q,
    const float* __restrict__ Wq, const float* __restrict__ Wk,
    const float* __restrict__ Wv, const float* __restrict__ Wo,
    unsigned short* __restrict__ qfh, unsigned short* __restrict__ qfl,
    unsigned short* __restrict__ WTh, unsigned short* __restrict__ WTl)
{
  int bx = blockIdx.x;
  if (bx < 3200) {
    int wave = threadIdx.x >> 6, lane = threadIdx.x & 63;
    int idx = bx * 4 + wave;                 // 0..12799
    int b = idx / SPAT, s = idx - b * SPAT;
    const float4 kv = *(const float4*)(k + (s * BSZ + b) * DM + lane * 4);
    const float4 wv = *(const float4*)(Wp + lane * 4);
    float sum = kv.x * wv.x + kv.y * wv.y + kv.z * wv.z + kv.w * wv.w;
    #pragma unroll
    for (int off = 32; off; off >>= 1) sum += __shfl_xor(sum, off);
    if (lane == 0) logits[idx] = sum + bp[0];
  } else if (bx < 4800) {
    int tg = (bx - 3200) * 256 + threadIdx.x;
    int row = tg >> 5;                       // b*1600+s
    int d0 = (tg & 31) * 8;
    int b = row / SPAT, s = row - b * SPAT;
    const float* src = q + (size_t)(s * BSZ + b) * DM + d0;
    float4 a = *(const float4*)src;
    float4 c = *(const float4*)(src + 4);
    float xs[8] = {a.x, a.y, a.z, a.w, c.x, c.y, c.z, c.w};
    bf16x8 hv, lv;
    #pragma unroll
    for (int j = 0; j < 8; ++j) {
      unsigned short hb = f2bf(xs[j]);
      hv[j] = (short)hb;
      lv[j] = (short)f2bf(xs[j] - bf2f(hb));
    }
    size_t dst = (((size_t)(row >> 4) * 8 + (d0 >> 5)) * 64
                  + ((d0 >> 3) & 3) * 16 + (row & 15)) * 8;
    *(bf16x8*)(qfh + dst) = hv;
    *(bf16x8*)(qfl + dst) = lv;
  } else {
    int mb = bx - 4800;
    int mat = mb >> 3, ktile = mb & 7;
    const float* W = (mat == 0) ? Wq : (mat == 1) ? Wk : (mat == 2) ? Wv : Wo;
    int n = threadIdx.x;
    int ntile = n >> 4, sig = n & 15;
    size_t base = (((size_t)(mat * 16 + ntile) * 8 + ktile) * 64 + sig) * 8;
    #pragma unroll 4
    for (int i = 0; i < 32; ++i) {
      int kk = ktile * 32 + i;
      float x = W[kk * DM + n];
      unsigned short hb = f2bf(x);
      size_t dst = base + (size_t)(i >> 3) * 128 + (i & 7);
      WTh[dst] = hb;
      WTl[dst] = (unsigned short)f2bf(x - bf2f(hb));
    }
  }
}

// -------- K2: per-batch softmax -> entropy -> gaussian conv (512 thr) --------
__global__ __launch_bounds__(512) void entropy_kernel(
    const float* __restrict__ logits, const float* __restrict__ gk,
    float* __restrict__ smooth)
{
  int b = blockIdx.x;
  int t = threadIdx.x;
  const float* L = logits + b * SPAT;
  __shared__ float entpad[SPAT + 28];
  __shared__ float red[512];

  for (int i = t; i < SPAT + 28; i += 512) entpad[i] = 0.f;

  float m = -INFINITY;
  for (int i = t; i < SPAT; i += 512) m = fmaxf(m, L[i]);
  red[t] = m; __syncthreads();
  for (int o = 256; o; o >>= 1) { if (t < o) red[t] = fmaxf(red[t], red[t + o]); __syncthreads(); }
  m = red[0]; __syncthreads();

  float lsum = 0.f;
  for (int i = t; i < SPAT; i += 512) {
    float e = expf(L[i] - m);
    entpad[14 + i] = e;
    lsum += e;
  }
  red[t] = lsum; __syncthreads();
  for (int o = 256; o; o >>= 1) { if (t < o) red[t] += red[t + o]; __syncthreads(); }
  float S = red[0]; __syncthreads();

  for (int i = t; i < SPAT; i += 512) {
    float p = entpad[14 + i] / S + 1e-8f;
    entpad[14 + i] = -p * logf(p) / 0.6931471805599453f;
  }
  __syncthreads();

  for (int i = t; i < SPAT; i += 512) {
    float acc = 0.f;
    #pragma unroll
    for (int u = 0; u < 29; ++u) acc += entpad[i + u] * gk[28 - u];
    smooth[b * SPAT + i] = acc;
  }
}

// -------- K3: cluster size; wave w = batch w, shfl-reduce, no atomics --------
__global__ __launch_bounds__(512) void clsize_kernel(
    const float* __restrict__ smooth, const float* __restrict__ sobel,
    int* __restrict__ meta)
{
  __shared__ int cnts[8];
  int t = threadIdx.x;
  int w = t >> 6, lane = t & 63;
  float sb0 = sobel[0], sb1 = sobel[1], sb2 = sobel[2];
  const float* sm = smooth + w * SPAT;
  int local = 0;
  for (int i = 1 + lane; i < SPAT; i += 64) {
    float smL = (i >= 2) ? sm[i - 2] : 0.f;
    float a = sm[i - 1];
    float c = sm[i];
    float smR = (i + 1 < SPAT) ? sm[i + 1] : 0.f;
    float stepPrev = smL * sb2 + a * sb1 + c * sb0;
    float stepCur  = a * sb2 + c * sb1 + smR * sb0;
    local += ((stepPrev > 0.f) != (stepCur > 0.f));
  }
  #pragma unroll
  for (int off = 32; off; off >>= 1) local += __shfl_xor(local, off);
  if (lane == 0) cnts[w] = local;
  __syncthreads();
  if (t == 0) {
    float msum = 0.f;
    for (int b = 0; b < BSZ; ++b) msum += 1600.f / (float)(cnts[b] + 1);
    float mean = msum / 8.f;
    int C = (int)rintf(mean);
    if (C < 1) C = 1;
    int rem = SPAT % C;
    meta[0] = C; meta[1] = rem / 2; meta[2] = rem; meta[3] = (SPAT - rem) / C;
  }
}

// -------- K4: cluster pooling; serial per-thread softmax (no barriers),
// emits kc/vc as bf16 hi/lo A-fragments --------
__global__ __launch_bounds__(256) void cluster_kernel(
    const float* __restrict__ k, const float* __restrict__ v,
    const float* __restrict__ smooth, const int* __restrict__ meta,
    unsigned short* __restrict__ kcfh, unsigned short* __restrict__ kcfl,
    unsigned short* __restrict__ vcfh, unsigned short* __restrict__ vcfl)
{
  int c = blockIdx.x, b = blockIdx.y;
  int C = meta[0], lo = meta[1], n_cl = meta[3];
  if (c >= n_cl) return;
  const float* sm = smooth + b * SPAT + lo + c * C;

  float m = sm[0];
  for (int j = 1; j < C; ++j) m = fmaxf(m, sm[j]);
  float S = 0.f;
  for (int j = 0; j < C; ++j) S += __expf(sm[j] - m);
  float invS = 1.f / S;

  int d = threadIdx.x;
  int s0 = lo + c * C;
  const float* kp = k + (s0 * BSZ + b) * DM + d;
  const float* vp = v + (s0 * BSZ + b) * DM + d;
  float ak = 0.f, av = 0.f;
  for (int j = 0; j < C; ++j) {
    float wj = __expf(sm[j] - m) * invS;
    ak += wj * kp[0];
    av += wj * vp[0];
    kp += BSZ * DM; vp += BSZ * DM;
  }
  int rowg = b * SPAT + c;
  size_t dst = (((size_t)(rowg >> 4) * 8 + (d >> 5)) * 64
                + ((d >> 3) & 3) * 16 + (rowg & 15)) * 8 + (d & 7);
  unsigned short hb = f2bf(ak);
  kcfh[dst] = hb; kcfl[dst] = (unsigned short)f2bf(ak - bf2f(hb));
  hb = f2bf(av);
  vcfh[dst] = hb; vcfl[dst] = (unsigned short)f2bf(av - bf2f(hb));
}

// -------- shared GEMM body: fragment-linear operands, bf16x3 --------
// epi: 0 = bf16 hi/lo [bh][s|c][32]
//      1 = K=16 V^T A-frags [bh][c16][dhalf][lane][4]
//      2 = fp32 out[(s*8+b)*256+n]
// kt loop unroll 2: doubles loads in flight (round-17 PMC: GEMMs are
// load-latency-bound at unroll 1). Full unroll was the round-8 disaster;
// 2 is the controlled middle.
static __device__ __forceinline__ void gemm_body(
    const unsigned short* __restrict__ Afh, const unsigned short* __restrict__ Afl,
    const unsigned short* __restrict__ Bfh, const unsigned short* __restrict__ Bfl,
    const float* __restrict__ bias,
    unsigned short* __restrict__ Oh, unsigned short* __restrict__ Ol,
    float* __restrict__ Of, int epi, int skipcl, const int* __restrict__ meta)
{
  int row0blk = blockIdx.x * 64;
  if (skipcl && (row0blk % SPAT) >= meta[3]) return;
  int wv = threadIdx.x >> 6, l = threadIdx.x & 63;
  int g = l >> 4, sig = l & 15;
  int row0 = row0blk + wv * 16;
  int rtile = row0 >> 4;
  int col0 = blockIdx.y * 64;
  int ntile0 = col0 >> 4;

  f32x4 acc[4] = {{0.f,0.f,0.f,0.f},{0.f,0.f,0.f,0.f},{0.f,0.f,0.f,0.f},{0.f,0.f,0.f,0.f}};

  #pragma unroll 2
  for (int kt = 0; kt < 8; ++kt) {
    size_t ao = (((size_t)rtile * 8 + kt) * 64 + l) * 8;
    bf16x8 ah = *(const bf16x8*)(Afh + ao);
    bf16x8 al = *(const bf16x8*)(Afl + ao);
    #pragma unroll
    for (int nt = 0; nt < 4; ++nt) {
      size_t bo = (((size_t)(ntile0 + nt) * 8 + kt) * 64 + l) * 8;
      bf16x8 bh = *(const bf16x8*)(Bfh + bo);
      bf16x8 bl = *(const bf16x8*)(Bfl + bo);
      acc[nt] = __builtin_amdgcn_mfma_f32_16x16x32_bf16(ah, bh, acc[nt], 0, 0, 0);
      acc[nt] = __builtin_amdgcn_mfma_f32_16x16x32_bf16(al, bh, acc[nt], 0, 0, 0);
      acc[nt] = __builtin_amdgcn_mfma_f32_16x16x32_bf16(ah, bl, acc[nt], 0, 0, 0);
    }
  }

  int bb = row0 / SPAT;
  int sbase = row0 - bb * SPAT + 4 * g;
  #pragma unroll
  for (int nt = 0; nt < 4; ++nt) {
    int n = col0 + nt * 16 + sig;
    float bi = bias[n];
    if (epi == 0) {
      int h = n >> 5, dl = n & 31;
      size_t base = (size_t)(bb * NH + h) * SPAT * DH + dl;
      #pragma unroll
      for (int r = 0; r < 4; ++r) {
        float x = acc[nt][r] + bi;
        unsigned short hb = f2bf(x);
        size_t dst = base + (size_t)(sbase + r) * DH;
        Oh[dst] = hb;
        Ol[dst] = (unsigned short)f2bf(x - bf2f(hb));
      }
    } else if (epi == 1) {
      int h = n >> 5;
      int bh = bb * NH + h;
      int dhalf = (n & 31) >> 4;
      int mrow = n & 15;
      #pragma unroll
      for (int r = 0; r < 4; ++r) {
        int c = sbase + r;
        float x = acc[nt][r] + bi;
        unsigned short hb = f2bf(x);
        size_t dst = ((((size_t)bh * NC16 + (c >> 4)) * 2 + dhalf) * 64
                      + ((c >> 2) & 3) * 16 + mrow) * 4 + (c & 3);
        Oh[dst] = hb;
        Ol[dst] = (unsigned short)f2bf(x - bf2f(hb));
      }
    } else {
      #pragma unroll
      for (int r = 0; r < 4; ++r) {
        float x = acc[nt][r] + bi;
        Of[(size_t)((sbase + r) * BSZ + bb) * DM + n] = x;
      }
    }
  }
}

// -------- K5a: fused Q/K/V projection GEMMs (blockIdx.z selects) --------
__global__ __launch_bounds__(256) void mfma_gemm_qkv_kernel(
    const unsigned short* __restrict__ qfh, const unsigned short* __restrict__ qfl,
    const unsigned short* __restrict__ kcfh, const unsigned short* __restrict__ kcfl,
    const unsigned short* __restrict__ vcfh, const unsigned short* __restrict__ vcfl,
    const unsigned short* __restrict__ WTfh, const unsigned short* __restrict__ WTfl,
    const float* __restrict__ bq, const float* __restrict__ bk, const float* __restrict__ bv,
    unsigned short* __restrict__ Qh, unsigned short* __restrict__ Ql,
    unsigned short* __restrict__ Kh, unsigned short* __restrict__ Kl,
    unsigned short* __restrict__ Vth, unsigned short* __restrict__ Vtl,
    const int* __restrict__ meta)
{
  int z = blockIdx.z;
  if (z == 0) {
    gemm_body(qfh, qfl, WTfh, WTfl, bq, Qh, Ql, nullptr, 0, 0, meta);
  } else if (z == 1) {
    gemm_body(kcfh, kcfl, WTfh + DM * DM, WTfl + DM * DM, bk, Kh, Kl, nullptr, 0, 1, meta);
  } else {
    gemm_body(vcfh, vcfl, WTfh + 2 * DM * DM, WTfl + 2 * DM * DM, bv, Vth, Vtl, nullptr, 1, 1, meta);
  }
}

// -------- K5b: output GEMM (epi=2, fp32 out + transpose) --------
__global__ __launch_bounds__(256) void mfma_gemm_o_kernel(
    const unsigned short* __restrict__ Afh, const unsigned short* __restrict__ Afl,
    const unsigned short* __restrict__ Bfh, const unsigned short* __restrict__ Bfl,
    const float* __restrict__ bias, float* __restrict__ Of,
    const int* __restrict__ meta)
{
  gemm_body(Afh, Afl, Bfh, Bfl, bias, nullptr, nullptr, Of, 2, 0, meta);
}

// -------- K6: MFMA attention (XCD-pinned grid + intra-block wave stagger).
// Grid (bh=64, sblk=25): XCD = bh % 8 -> per-XCD working set 3.3 MB fits
// L2 (round-17: FETCH 26->9 MB). Wave w starts at chunk w*nch/4: the 4
// waves pull DIFFERENT L2 lines concurrently (higher per-CU MLP) while
// staying in the bh-pinned set (unlike round-16's cross-block rotation,
// FETCH cannot rise). QK bf16x3; PV K=16 fed directly from QK output regs.
__global__ __launch_bounds__(256) void attn_mfma_kernel(
    const unsigned short* __restrict__ Qh, const unsigned short* __restrict__ Ql,
    const unsigned short* __restrict__ Kh, const unsigned short* __restrict__ Kl,
    const unsigned short* __restrict__ Vth, const unsigned short* __restrict__ Vtl,
    const int* __restrict__ meta,
    unsigned short* __restrict__ ctxfh, unsigned short* __restrict__ ctxfl)
{
  int bh = blockIdx.x;                      // 0..63 -> XCD = bh % 8
  int b = bh >> 3, h = bh & 7;
  int t = threadIdx.x;
  int w = t >> 6, l = t & 63;
  int g = l >> 4, sig = l & 15;
  int n_cl = meta[3];
  int s = blockIdx.y * 64 + w * 16 + sig;   // 25*64 = 1600

  size_t qoff = ((size_t)bh * SPAT + s) * DH + g * 8;
  bf16x8 qh = *(const bf16x8*)(Qh + qoff);
  bf16x8 ql = *(const bf16x8*)(Ql + qoff);

  const unsigned short* Kbh = Kh + (size_t)bh * SPAT * DH;
  const unsigned short* Kbl = Kl + (size_t)bh * SPAT * DH;
  const unsigned short* Vbh = Vth + (size_t)bh * NC16 * 2 * 64 * 4;
  const unsigned short* Vbl = Vtl + (size_t)bh * NC16 * 2 * 64 * 4;

  f32x4 o0 = {0.f, 0.f, 0.f, 0.f}, o1 = {0.f, 0.f, 0.f, 0.f};
  float m = -1e30f, lsum = 0.f;

  int nch = (n_cl + 63) >> 6;
  int start = (w * nch) >> 2;               // {0, n/4, n/2, 3n/4}

  for (int i = 0; i < nch; ++i) {
    int ci = start + i;
    if (ci >= nch) ci -= nch;
    int c0 = ci * 64;

    // ---- QK^T: rows cr = c0+ct*16+sig <= 1599 always (c0 <= 1536) ----
    f32x4 sc[4];
    __builtin_amdgcn_s_setprio(1);
    #pragma unroll
    for (int ct = 0; ct < 4; ++ct) {
      size_t ko = (size_t)(c0 + ct * 16 + sig) * DH + g * 8;
      bf16x8 kh = *(const bf16x8*)(Kbh + ko);
      bf16x8 kl = *(const bf16x8*)(Kbl + ko);
      f32x4 a = {0.f, 0.f, 0.f, 0.f};
      a = __builtin_amdgcn_mfma_f32_16x16x32_bf16(kh, qh, a, 0, 0, 0);
      a = __builtin_amdgcn_mfma_f32_16x16x32_bf16(kh, ql, a, 0, 0, 0);
      a = __builtin_amdgcn_mfma_f32_16x16x32_bf16(kl, qh, a, 0, 0, 0);
      sc[ct] = a;
    }
    __builtin_amdgcn_s_setprio(0);

    // ---- V A-frags for this chunk: issue BEFORE softmax (independent) ----
    bf16x4 vfh[4][2], vfl[4][2];
    #pragma unroll
    for (int ct = 0; ct < 4; ++ct) {
      int c16 = (c0 >> 4) + ct;             // <= 99, always in-buffer
      #pragma unroll
      for (int dh2 = 0; dh2 < 2; ++dh2) {
        size_t vo = (((size_t)c16 * 2 + dh2) * 64 + l) * 4;
        vfh[ct][dh2] = *(const bf16x4*)(Vbh + vo);
        vfl[ct][dh2] = *(const bf16x4*)(Vbl + vo);
      }
    }

    if (c0 + 64 > n_cl) {                   // tail chunk only: mask
      #pragma unroll
      for (int ct = 0; ct < 4; ++ct) {
        #pragma unroll
        for (int r = 0; r < 4; ++r) {
          int c = c0 + ct * 16 + g * 4 + r;
          if (c >= n_cl) sc[ct][r] = -INFINITY;
        }
      }
    }
    float mc = sc[0][0];
    #pragma unroll
    for (int ct = 0; ct < 4; ++ct) {
      #pragma unroll
      for (int r = 0; r < 4; ++r) mc = fmaxf(mc, sc[ct][r]);
    }
    mc = fmaxf(mc, __shfl_xor(mc, 16));
    mc = fmaxf(mc, __shfl_xor(mc, 32));
    float nm = fmaxf(m, mc);
    float corr = __expf(m - nm);
    m = nm;
    lsum *= corr; o0 *= corr; o1 *= corr;
    float ls0 = 0.f, ls1 = 0.f;
    #pragma unroll
    for (int ct = 0; ct < 4; ++ct) {
      #pragma unroll
      for (int r = 0; r < 4; ++r) {
        float p = __expf(sc[ct][r] - m);
        sc[ct][r] = p;
        if (ct < 2) ls0 += p; else ls1 += p;
      }
    }
    lsum += ls0 + ls1;

    // ---- PV: P already in B-frag layout for 16x16x16 (k = 4g+j) ----
    __builtin_amdgcn_s_setprio(1);
    #pragma unroll
    for (int ct = 0; ct < 4; ++ct) {
      if (c0 + ct * 16 >= n_cl) continue;   // wave-uniform skip
      bf16x4 pb;
      #pragma unroll
      for (int j = 0; j < 4; ++j) pb[j] = (short)f2bf(sc[ct][j]);
      o0 = __builtin_amdgcn_mfma_f32_16x16x16bf16_1k(vfh[ct][0], pb, o0, 0, 0, 0);
      o0 = __builtin_amdgcn_mfma_f32_16x16x16bf16_1k(vfl[ct][0], pb, o0, 0, 0, 0);
      o1 = __builtin_amdgcn_mfma_f32_16x16x16bf16_1k(vfh[ct][1], pb, o1, 0, 0, 0);
      o1 = __builtin_amdgcn_mfma_f32_16x16x16bf16_1k(vfl[ct][1], pb, o1, 0, 0, 0);
    }
    __builtin_amdgcn_s_setprio(0);
  }

  // ---- finalize: write O^T frags into ctx A-fragment layout ----
  lsum += __shfl_xor(lsum, 16);
  lsum += __shfl_xor(lsum, 32);
  float inv = 1.f / (lsum * 32.f);
  int rowg = b * SPAT + s;                  // rowg&15 == sig
  size_t tb = (((size_t)(rowg >> 4) * 8 + h) * 64 + sig) * 8 + (g & 1) * 4;
  size_t off0 = tb + (size_t)(g >> 1) * 128;        // d = 4g+r  (ktile=h)
  size_t off1 = tb + (size_t)(2 + (g >> 1)) * 128;  // d = 16+4g+r
  u16x4 hv0, lv0, hv1, lv1;
  #pragma unroll
  for (int r = 0; r < 4; ++r) {
    float x0 = o0[r] * inv;
    unsigned short h0 = f2bf(x0);
    hv0[r] = h0; lv0[r] = (unsigned short)f2bf(x0 - bf2f(h0));
    float x1 = o1[r] * inv;
    unsigned short h1 = f2bf(x1);
    hv1[r] = h1; lv1[r] = (unsigned short)f2bf(x1 - bf2f(h1));
  }
  *(u16x4*)(ctxfh + off0) = hv0;
  *(u16x4*)(ctxfl + off0) = lv0;
  *(u16x4*)(ctxfh + off1) = hv1;
  *(u16x4*)(ctxfl + off1) = lv1;
}

extern "C" void kernel_launch(void* const* d_in, const int* in_sizes, int n_in,
                              void* d_out, int out_size, void* d_ws, size_t ws_size,
                              hipStream_t stream) {
  const float* q  = (const float*)d_in[0];
  const float* k  = (const float*)d_in[1];
  const float* v  = (const float*)d_in[2];
  const float* Wq = (const float*)d_in[5];
  const float* bq = (const float*)d_in[6];
  const float* Wk = (const float*)d_in[7];
  const float* bk = (const float*)d_in[8];
  const float* Wv = (const float*)d_in[9];
  const float* bv = (const float*)d_in[10];
  const float* Wo = (const float*)d_in[11];
  const float* bo = (const float*)d_in[12];
  const float* Wp = (const float*)d_in[13];
  const float* bp = (const float*)d_in[14];
  const float* gk = (const float*)d_in[15];
  const float* sb = (const float*)d_in[16];
  float* out = (float*)d_out;

  const size_t NE = (size_t)BSZ * SPAT * DM;                 // 3276800
  char* ws = (char*)d_ws;
  int*   meta   = (int*)ws;                                  // 256 B
  float* logits = (float*)(ws + 256);                        // 12800 f32
  float* smooth = logits + BSZ * SPAT;                       // 12800 f32
  unsigned short* kcfh = (unsigned short*)(ws + 256 + 2 * BSZ * SPAT * 4);
  unsigned short* kcfl = kcfh + NE;
  unsigned short* vcfh = kcfl + NE;
  unsigned short* vcfl = vcfh + NE;
  unsigned short* qfh  = vcfl + NE;
  unsigned short* qfl  = qfh + NE;
  unsigned short* Qh   = qfl + NE;
  unsigned short* Ql   = Qh + NE;
  unsigned short* Kh   = Ql + NE;
  unsigned short* Kl   = Kh + NE;
  unsigned short* Vth  = Kl + NE;   // NOT aliased: QKV GEMMs fused in one
  unsigned short* Vtl  = Vth + NE;  // dispatch — z=0 reads qf while z=2 writes
  unsigned short* WTfh = Vtl + NE;                           // 4*65536 u16
  unsigned short* WTfl = WTfh + 4 * DM * DM;
  unsigned short* ctxfh = kcfh;     // alias kcf (dead after fused QKV GEMM)
  unsigned short* ctxfl = kcfl;

  prep_logits_kernel<<<4832, 256, 0, stream>>>(
      k, Wp, bp, logits, q, Wq, Wk, Wv, Wo, qfh, qfl, WTfh, WTfl);
  entropy_kernel<<<BSZ, 512, 0, stream>>>(logits, gk, smooth);
  clsize_kernel<<<1, 512, 0, stream>>>(smooth, sb, meta);
  cluster_kernel<<<dim3(SPAT, BSZ), 256, 0, stream>>>(
      k, v, smooth, meta, kcfh, kcfl, vcfh, vcfl);
  mfma_gemm_qkv_kernel<<<dim3(200, 4, 3), 256, 0, stream>>>(
      qfh, qfl, kcfh, kcfl, vcfh, vcfl, WTfh, WTfl, bq, bk, bv,
      Qh, Ql, Kh, Kl, Vth, Vtl, meta);
  attn_mfma_kernel<<<dim3(64, 25), 256, 0, stream>>>(
      Qh, Ql, Kh, Kl, Vth, Vtl, meta, ctxfh, ctxfl);
  mfma_gemm_o_kernel<<<dim3(200, 4), 256, 0, stream>>>(
      ctxfh, ctxfl, WTfh + 3 * DM * DM, WTfl + 3 * DM * DM, bo, out, meta);
}